// Round 8
// baseline (2443.428 us; speedup 1.0000x reference)
//
#include <hip/hip_runtime.h>

#define DEV __device__ __forceinline__

typedef short s8v __attribute__((ext_vector_type(8)));
typedef float f4v __attribute__((ext_vector_type(4)));

DEV short f2bf(float f) {
  unsigned u = __float_as_uint(f);
  u += 0x7FFFu + ((u >> 16) & 1u);
  return (short)(u >> 16);
}
DEV short f2bf_fast(float f) {           // round-to-nearest, no tie-to-even (P in (0,1])
  return (short)((__float_as_uint(f) + 0x8000u) >> 16);
}
DEV float bf2f(short s) { return __uint_as_float(((unsigned)(unsigned short)s) << 16); }

DEV void gld_lds16(const short* g, short* l) {
  __builtin_amdgcn_global_load_lds(
      (const __attribute__((address_space(1))) void*)g,
      (__attribute__((address_space(3))) void*)l, 16, 0, 0);
}

// XCD-bijective swizzle (m204)
DEV int xcd_swz(int id, int nwg) {
  int q8 = nwg >> 3, r8 = nwg & 7, xcd = id & 7, off = id >> 3;
  return (xcd < r8) ? (xcd * (q8 + 1) + off) : (r8 * (q8 + 1) + (xcd - r8) * q8 + off);
}

// ================= 64xBN tile bf16 BT GEMM, dbuf + chunk-swizzle =================
// BN=128: waves 1x4 (64x32 each). BN=64: waves 2x2 (32x32).
// flags: 1=+bias[col], 2=exact GELU, 4=accumulate into fp32 C, 8=bf16 out
template<int BN>
__global__ __launch_bounds__(256) void gemm_t(
    const short* __restrict__ A, const short* __restrict__ B, void* __restrict__ Cv,
    const float* __restrict__ bias,
    int M, int N, int K, int lda, int ldb, int ldc, int flags)
{
  constexpr int BPASS = BN / 32;
  constexpr int MI = (BN == 128) ? 4 : 2;
  __shared__ __align__(16) short As[2][64 * 64];
  __shared__ __align__(16) short Bs[2][BN * 64];
  int nwg = gridDim.x * gridDim.y;
  int idl = blockIdx.y * gridDim.x + blockIdx.x;
  int swz = xcd_swz(idl, nwg);
  int bx = swz % gridDim.x, by = swz / gridDim.x;
  int m0 = by * 64, n0 = bx * BN;
  int tid = threadIdx.x, lane = tid & 63, w = tid >> 6;
  int lr = lane & 15, kg = lane >> 4;
  int wrb = (BN == 128) ? 0 : (w >> 1) * 32;
  int wcb = (BN == 128) ? w * 32 : (w & 1) * 32;
  f4v acc[MI][2] = {};
  int NT = K >> 6;

#define STAGE(bufi, k0)                                                   \
  {                                                                       \
    _Pragma("unroll")                                                     \
    for (int p = 0; p < 2; ++p) {                                         \
      int ch = p * 256 + w * 64 + lane;                                   \
      int row = ch >> 3, c = (ch & 7) ^ (row & 7);                        \
      gld_lds16(A + (long)(m0 + row) * lda + (k0) + c * 8,                \
                &As[bufi][(p * 256 + w * 64) * 8]);                       \
    }                                                                     \
    _Pragma("unroll")                                                     \
    for (int p = 0; p < BPASS; ++p) {                                     \
      int ch = p * 256 + w * 64 + lane;                                   \
      int row = ch >> 3, c = (ch & 7) ^ (row & 7);                        \
      gld_lds16(B + (long)(n0 + row) * ldb + (k0) + c * 8,                \
                &Bs[bufi][(p * 256 + w * 64) * 8]);                       \
    }                                                                     \
  }

  STAGE(0, 0)
  for (int t = 0; t < NT; ++t) {
    int buf = t & 1;
    if (t + 1 < NT) {
      STAGE(buf ^ 1, (t + 1) * 64)
      if constexpr (BN == 128)
        asm volatile("s_waitcnt vmcnt(6)" ::: "memory");
      else
        asm volatile("s_waitcnt vmcnt(4)" ::: "memory");
    } else {
      asm volatile("s_waitcnt vmcnt(0)" ::: "memory");
    }
    __builtin_amdgcn_s_barrier();
    #pragma unroll
    for (int ks = 0; ks < 2; ++ks) {
      s8v av[MI], bv[2];
      #pragma unroll
      for (int mi = 0; mi < MI; ++mi) {
        int row = wrb + mi * 16 + lr;
        int sl = (ks * 4 + kg) ^ (row & 7);
        av[mi] = *(const s8v*)&As[buf][row * 64 + sl * 8];
      }
      #pragma unroll
      for (int ni = 0; ni < 2; ++ni) {
        int row = wcb + ni * 16 + lr;
        int sl = (ks * 4 + kg) ^ (row & 7);
        bv[ni] = *(const s8v*)&Bs[buf][row * 64 + sl * 8];
      }
      #pragma unroll
      for (int mi = 0; mi < MI; ++mi)
        #pragma unroll
        for (int ni = 0; ni < 2; ++ni)
          acc[mi][ni] = __builtin_amdgcn_mfma_f32_16x16x32_bf16(av[mi], bv[ni], acc[mi][ni], 0, 0, 0);
    }
    asm volatile("s_waitcnt lgkmcnt(0)" ::: "memory");
    __builtin_amdgcn_s_barrier();
  }
#undef STAGE

  float* Cf = (float*)Cv;
  short* Cb = (short*)Cv;
  #pragma unroll
  for (int mi = 0; mi < MI; ++mi)
    #pragma unroll
    for (int ni = 0; ni < 2; ++ni) {
      int col = n0 + wcb + ni * 16 + lr;
      float bvv = (flags & 1) ? bias[col] : 0.f;
      #pragma unroll
      for (int j = 0; j < 4; ++j) {
        int row = m0 + wrb + mi * 16 + kg * 4 + j;
        if (row >= M) continue;
        float v = acc[mi][ni][j] + bvv;
        if (flags & 2) v = 0.5f * v * (1.f + erff(v * 0.70710678118f));
        long ci = (long)row * ldc + col;
        if (flags & 8) Cb[ci] = f2bf(v);
        else { if (flags & 4) v += Cf[ci]; Cf[ci] = v; }
      }
    }
}

// ================= 128x128 tile, 4 waves 2x2, 64x64 per wave =================
// Better MFMA:ds_read ratio (2:1) for the larger GEMMs (qkv, ffn1).
__global__ __launch_bounds__(256) void gemm128(
    const short* __restrict__ A, const short* __restrict__ B, void* __restrict__ Cv,
    const float* __restrict__ bias,
    int M, int N, int K, int lda, int ldb, int ldc, int flags)
{
  __shared__ __align__(16) short As[2][128 * 64];   // 32 KB
  __shared__ __align__(16) short Bs[2][128 * 64];   // 32 KB
  int nwg = gridDim.x * gridDim.y;
  int idl = blockIdx.y * gridDim.x + blockIdx.x;
  int swz = xcd_swz(idl, nwg);
  int bx = swz % gridDim.x, by = swz / gridDim.x;
  int m0 = by * 128, n0 = bx * 128;
  int tid = threadIdx.x, lane = tid & 63, w = tid >> 6;
  int lr = lane & 15, kg = lane >> 4;
  int wrb = (w >> 1) * 64, wcb = (w & 1) * 64;
  f4v acc[4][4] = {};
  int NT = K >> 6;

#define STAGE(bufi, k0)                                                   \
  {                                                                       \
    _Pragma("unroll")                                                     \
    for (int p = 0; p < 4; ++p) {                                         \
      int ch = p * 256 + w * 64 + lane;                                   \
      int row = ch >> 3, c = (ch & 7) ^ (row & 7);                        \
      gld_lds16(A + (long)(m0 + row) * lda + (k0) + c * 8,                \
                &As[bufi][(p * 256 + w * 64) * 8]);                       \
      gld_lds16(B + (long)(n0 + row) * ldb + (k0) + c * 8,                \
                &Bs[bufi][(p * 256 + w * 64) * 8]);                       \
    }                                                                     \
  }

  STAGE(0, 0)
  for (int t = 0; t < NT; ++t) {
    int buf = t & 1;
    if (t + 1 < NT) {
      STAGE(buf ^ 1, (t + 1) * 64)
      asm volatile("s_waitcnt vmcnt(8)" ::: "memory");   // retire tile-t's 8 loads
    } else {
      asm volatile("s_waitcnt vmcnt(0)" ::: "memory");
    }
    __builtin_amdgcn_s_barrier();
    #pragma unroll
    for (int ks = 0; ks < 2; ++ks) {
      s8v av[4], bv[4];
      #pragma unroll
      for (int mi = 0; mi < 4; ++mi) {
        int row = wrb + mi * 16 + lr;
        int sl = (ks * 4 + kg) ^ (row & 7);
        av[mi] = *(const s8v*)&As[buf][row * 64 + sl * 8];
      }
      #pragma unroll
      for (int ni = 0; ni < 4; ++ni) {
        int row = wcb + ni * 16 + lr;
        int sl = (ks * 4 + kg) ^ (row & 7);
        bv[ni] = *(const s8v*)&Bs[buf][row * 64 + sl * 8];
      }
      #pragma unroll
      for (int mi = 0; mi < 4; ++mi)
        #pragma unroll
        for (int ni = 0; ni < 4; ++ni)
          acc[mi][ni] = __builtin_amdgcn_mfma_f32_16x16x32_bf16(av[mi], bv[ni], acc[mi][ni], 0, 0, 0);
    }
    asm volatile("s_waitcnt lgkmcnt(0)" ::: "memory");
    __builtin_amdgcn_s_barrier();
  }
#undef STAGE

  float* Cf = (float*)Cv;
  short* Cb = (short*)Cv;
  #pragma unroll
  for (int mi = 0; mi < 4; ++mi)
    #pragma unroll
    for (int ni = 0; ni < 4; ++ni) {
      int col = n0 + wcb + ni * 16 + lr;
      float bvv = (flags & 1) ? bias[col] : 0.f;
      #pragma unroll
      for (int j = 0; j < 4; ++j) {
        int row = m0 + wrb + mi * 16 + kg * 4 + j;
        if (row >= M) continue;
        float v = acc[mi][ni][j] + bvv;
        if (flags & 2) v = 0.5f * v * (1.f + erff(v * 0.70710678118f));
        long ci = (long)row * ldc + col;
        if (flags & 8) Cb[ci] = f2bf(v);
        else { if (flags & 4) v += Cf[ci]; Cf[ci] = v; }
      }
    }
}

// ---------------- fused flash attention (unsplit, dbuf K/V, setprio) ----------------
// qkv: [4][1025][1536] bf16 (Q +0, K +64, V +128 per head zh*192)
// O:   [4][1025][512]  bf16
__global__ __launch_bounds__(256) void flash_k(
    const short* __restrict__ qkv, short* __restrict__ O)
{
  int swz = xcd_swz(blockIdx.x, 544);
  int z = swz / 17, qt = swz - z * 17;
  int zb = z >> 3, zh = z & 7;
  const short* base = qkv + (long)zb * 1025 * 1536 + zh * 192;
  const short* Qg = base;
  const short* Kg = base + 64;
  const short* Vg = base + 128;
  int q0 = qt * 64;
  int tid = threadIdx.x, lane = tid & 63, w = tid >> 6;
  int lr = lane & 15, kg = lane >> 4;

  __shared__ __align__(16) short QPs[64][72];   // Q in prologue; per-wave P after
  __shared__ __align__(16) short Ks[2][64 * 64];
  __shared__ __align__(16) short Vt[2][64][72];

  for (int s = tid; s < 512; s += 256) {
    int row = s >> 3, ch = s & 7;
    s8v v = {};
    if (q0 + row < 1025) v = *(const s8v*)(Qg + (long)(q0 + row) * 1536 + ch * 8);
    *(s8v*)&QPs[row][ch * 8] = v;
  }
  __syncthreads();
  s8v aq[2];
  aq[0] = *(const s8v*)&QPs[w * 16 + lr][kg * 8];
  aq[1] = *(const s8v*)&QPs[w * 16 + lr][32 + kg * 8];

#define STAGE_K(bufi, kv0)                                                 \
  {                                                                        \
    int s0 = w * 128;                                                      \
    _Pragma("unroll")                                                      \
    for (int i = 0; i < 2; ++i) {                                          \
      int s = s0 + i * 64 + lane;                                          \
      int row = s >> 3, c = (s & 7) ^ (row & 7);                           \
      gld_lds16(Kg + (long)((kv0) + row) * 1536 + c * 8,                   \
                &Ks[bufi][(s0 + i * 64) * 8]);                             \
    }                                                                      \
  }

  f4v acc[4] = {};
  float m_run[4], l_run[4];
  #pragma unroll
  for (int j = 0; j < 4; ++j) { m_run[j] = -3.0e38f; l_run[j] = 0.f; }

  // prologue: tile 0
  STAGE_K(0, 0)
  #pragma unroll
  for (int p = 0; p < 2; ++p) {
    int s = p * 256 + tid;
    int key = s & 63, ch = s >> 6;
    s8v v = *(const s8v*)(Vg + (long)key * 1536 + ch * 8);
    #pragma unroll
    for (int j = 0; j < 8; ++j) Vt[0][ch * 8 + j][key] = v[j];
  }
  asm volatile("s_waitcnt vmcnt(0)" ::: "memory");
  asm volatile("s_waitcnt lgkmcnt(0)" ::: "memory");
  __builtin_amdgcn_s_barrier();

  for (int kt = 0; kt < 17; ++kt) {
    int cur = kt & 1;
    int kv0 = kt * 64;
    s8v vreg[2];
    int vok[2];
    if (kt < 16) {
      STAGE_K(cur ^ 1, kv0 + 64)
      #pragma unroll
      for (int p = 0; p < 2; ++p) {
        int s = p * 256 + tid;
        int key = (s & 63) + kv0 + 64, ch = s >> 6;
        vok[p] = key < 1025;
        vreg[p] = vok[p] ? *(const s8v*)(Vg + (long)key * 1536 + ch * 8) : s8v{};
      }
    }

    // S = Q K^T
    f4v sa[4] = {};
    __builtin_amdgcn_s_setprio(1);
    #pragma unroll
    for (int ni = 0; ni < 4; ++ni) {
      int row = ni * 16 + lr;
      #pragma unroll
      for (int ks = 0; ks < 2; ++ks) {
        int c = (ks * 4 + kg) ^ (row & 7);
        s8v bk = *(const s8v*)&Ks[cur][row * 64 + c * 8];
        sa[ni] = __builtin_amdgcn_mfma_f32_16x16x32_bf16(aq[ks], bk, sa[ni], 0, 0, 0);
      }
    }
    __builtin_amdgcn_s_setprio(0);
    // mask + online softmax
    float sv[4][4], pv[4][4], tm[4], ts[4];
    #pragma unroll
    for (int j = 0; j < 4; ++j) tm[j] = -3.0e38f;
    #pragma unroll
    for (int ni = 0; ni < 4; ++ni) {
      bool valid = (kv0 + ni * 16 + lr) < 1025;
      #pragma unroll
      for (int j = 0; j < 4; ++j) {
        float s = valid ? sa[ni][j] * 0.125f : -3.0e38f;
        sv[ni][j] = s;
        tm[j] = fmaxf(tm[j], s);
      }
    }
    #pragma unroll
    for (int o = 1; o < 16; o <<= 1)
      #pragma unroll
      for (int j = 0; j < 4; ++j) tm[j] = fmaxf(tm[j], __shfl_xor(tm[j], o));
    float scale[4], m_new[4];
    #pragma unroll
    for (int j = 0; j < 4; ++j) {
      m_new[j] = fmaxf(m_run[j], tm[j]);
      scale[j] = __expf(m_run[j] - m_new[j]);
      m_run[j] = m_new[j];
      ts[j] = 0.f;
    }
    #pragma unroll
    for (int ni = 0; ni < 4; ++ni)
      #pragma unroll
      for (int j = 0; j < 4; ++j) {
        float p = __expf(sv[ni][j] - m_new[j]);
        pv[ni][j] = p;
        ts[j] += p;
      }
    #pragma unroll
    for (int o = 1; o < 16; o <<= 1)
      #pragma unroll
      for (int j = 0; j < 4; ++j) ts[j] += __shfl_xor(ts[j], o);
    #pragma unroll
    for (int j = 0; j < 4; ++j) l_run[j] = l_run[j] * scale[j] + ts[j];
    #pragma unroll
    for (int ni = 0; ni < 4; ++ni)
      #pragma unroll
      for (int j = 0; j < 4; ++j) acc[ni][j] *= scale[j];

    // write next tile's V (reg loads auto-waited; hides under softmax)
    if (kt < 16) {
      #pragma unroll
      for (int p = 0; p < 2; ++p) {
        int s = p * 256 + tid;
        int key = s & 63, ch = s >> 6;
        s8v v = vok[p] ? vreg[p] : s8v{};
        #pragma unroll
        for (int j = 0; j < 8; ++j) Vt[cur ^ 1][ch * 8 + j][key] = v[j];
      }
    }

    // P -> per-wave LDS slice
    #pragma unroll
    for (int ni = 0; ni < 4; ++ni)
      #pragma unroll
      for (int j = 0; j < 4; ++j)
        QPs[w * 16 + kg * 4 + j][ni * 16 + lr] = f2bf_fast(pv[ni][j]);
    asm volatile("s_waitcnt lgkmcnt(0)" ::: "memory");
    // O += P V
    s8v ap[2];
    ap[0] = *(const s8v*)&QPs[w * 16 + lr][kg * 8];
    ap[1] = *(const s8v*)&QPs[w * 16 + lr][32 + kg * 8];
    __builtin_amdgcn_s_setprio(1);
    #pragma unroll
    for (int ni = 0; ni < 4; ++ni) {
      #pragma unroll
      for (int ks = 0; ks < 2; ++ks) {
        s8v bvv = *(const s8v*)&Vt[cur][ni * 16 + lr][ks * 32 + kg * 8];
        acc[ni] = __builtin_amdgcn_mfma_f32_16x16x32_bf16(ap[ks], bvv, acc[ni], 0, 0, 0);
      }
    }
    __builtin_amdgcn_s_setprio(0);
    asm volatile("s_waitcnt lgkmcnt(0)" ::: "memory");
    asm volatile("s_waitcnt vmcnt(0)" ::: "memory");
    __builtin_amdgcn_s_barrier();
  }
#undef STAGE_K

  float inv[4];
  #pragma unroll
  for (int j = 0; j < 4; ++j) inv[j] = 1.f / l_run[j];
  #pragma unroll
  for (int ni = 0; ni < 4; ++ni)
    #pragma unroll
    for (int j = 0; j < 4; ++j) {
      int row = q0 + w * 16 + kg * 4 + j;
      if (row < 1025)
        O[((long)(zb * 1025 + row)) * 512 + zh * 64 + ni * 16 + lr] = f2bf(acc[ni][j] * inv[j]);
    }
}

// ---------------- fused per-layer weight transpose+convert ----------------
DEV void tconv_body(const float* w, short* wt, int K, int N, int bx, int by, int tid)
{
  __shared__ float tile[32][33];
  int n0 = bx * 32, k0 = by * 32;
  int tx = tid & 31, ty = tid >> 5;
  #pragma unroll
  for (int j = 0; j < 4; ++j)
    tile[ty + j * 8][tx] = w[(long)(k0 + ty + j * 8) * N + n0 + tx];
  __syncthreads();
  #pragma unroll
  for (int j = 0; j < 4; ++j)
    wt[(long)(n0 + ty + j * 8) * K + k0 + tx] = f2bf(tile[tx][ty + j * 8]);
}

__global__ __launch_bounds__(256) void tconv4_k(
    const float* __restrict__ sq, const float* __restrict__ sm,
    const float* __restrict__ sf1, const float* __restrict__ sf2,
    short* __restrict__ dq, short* __restrict__ dm,
    short* __restrict__ df1, short* __restrict__ df2)
{
  int id = blockIdx.x, tid = threadIdx.x;
  if (id < 1152)       tconv_body(sq,  dq,  768, 1536, id % 48,          id / 48,          tid);
  else if (id < 1536)  tconv_body(sm,  dm,  512, 768,  (id - 1152) % 24, (id - 1152) / 24, tid);
  else if (id < 3072)  tconv_body(sf1, df1, 768, 2048, (id - 1536) % 64, (id - 1536) / 64, tid);
  else                 tconv_body(sf2, df2, 2048, 768, (id - 3072) % 24, (id - 3072) / 24, tid);
}

// ---------------- elementwise fp32 -> bf16 ----------------
__global__ __launch_bounds__(256) void cvt_k(const float* __restrict__ in,
    short* __restrict__ out, int n)
{
  int i = blockIdx.x * 256 + threadIdx.x;
  if (i < n) out[i] = f2bf(in[i]);
}

// ---------------- LayerNorm D=768 ----------------
DEV void st_ln(float* p, float v) { *p = v; }
DEV void st_ln(short* p, float v) { *p = f2bf(v); }

template<typename OT>
__global__ __launch_bounds__(256) void ln_k(const float* __restrict__ x,
    const float* __restrict__ g, const float* __restrict__ b,
    OT* __restrict__ y, int rows)
{
  int row = blockIdx.x;
  if (row >= rows) return;
  const float* xr = x + (long)row * 768;
  OT* yr = y + (long)row * 768;
  int t = threadIdx.x;
  float v0 = xr[t], v1 = xr[t + 256], v2 = xr[t + 512];
  float s = v0 + v1 + v2, s2 = v0 * v0 + v1 * v1 + v2 * v2;
  #pragma unroll
  for (int o = 32; o > 0; o >>= 1) { s += __shfl_down(s, o); s2 += __shfl_down(s2, o); }
  __shared__ float as_[4], as2_[4];
  if ((t & 63) == 0) { as_[t >> 6] = s; as2_[t >> 6] = s2; }
  __syncthreads();
  s = as_[0] + as_[1] + as_[2] + as_[3];
  s2 = as2_[0] + as2_[1] + as2_[2] + as2_[3];
  float mean = s * (1.f / 768.f);
  float var = s2 * (1.f / 768.f) - mean * mean;
  float r = rsqrtf(var + 1e-5f);
  st_ln(&yr[t],       (v0 - mean) * r * g[t]       + b[t]);
  st_ln(&yr[t + 256], (v1 - mean) * r * g[t + 256] + b[t + 256]);
  st_ln(&yr[t + 512], (v2 - mean) * r * g[t + 512] + b[t + 512]);
}

// ---------------- patch extraction ----------------
__global__ __launch_bounds__(256) void im2col_k(const float* __restrict__ x,
    short* __restrict__ A)
{
  int i = blockIdx.x * 256 + threadIdx.x;
  int k = i & 255, row = i >> 8;
  int px = k & 15, py = k >> 4;
  int gx = row & 31, gy = (row >> 5) & 31, b = row >> 10;
  A[i] = f2bf(x[((long)(b * 512) + gy * 16 + py) * 512 + gx * 16 + px]);
}

// ---------------- t = concat(cls, tok) + pos ----------------
__global__ __launch_bounds__(256) void assemble_k(const short* __restrict__ tok,
    const float* __restrict__ cls, const float* __restrict__ pos, float* __restrict__ t)
{
  int i = blockIdx.x * 256 + threadIdx.x;
  int d = i % 768; int rn = i / 768; int n = rn % 1025; int b = rn / 1025;
  float v = (n == 0) ? cls[d] : bf2f(tok[((long)(b * 1024 + n - 1)) * 768 + d]);
  t[i] = v + pos[n * 768 + d];
}

extern "C" void kernel_launch(void* const* d_in, const int* in_sizes, int n_in,
                              void* d_out, int out_size, void* d_ws, size_t ws_size,
                              hipStream_t stream)
{
  const float* x       = (const float*)d_in[0];
  const float* conv_w  = (const float*)d_in[1];
  const float* conv_b  = (const float*)d_in[2];
  const float* cls     = (const float*)d_in[3];
  const float* pos     = (const float*)d_in[4];
  const float* qkv_w   = (const float*)d_in[5];
  const float* merge_w = (const float*)d_in[6];
  const float* merge_b = (const float*)d_in[7];
  const float* ln1_s   = (const float*)d_in[8];
  const float* ln1_b   = (const float*)d_in[9];
  const float* ln2_s   = (const float*)d_in[10];
  const float* ln2_b   = (const float*)d_in[11];
  const float* ffn_w1  = (const float*)d_in[12];
  const float* ffn_b1  = (const float*)d_in[13];
  const float* ffn_w2  = (const float*)d_in[14];
  const float* ffn_b2  = (const float*)d_in[15];
  const float* lnf_s   = (const float*)d_in[16];
  const float* lnf_b   = (const float*)d_in[17];

  char* wsp = (char*)d_ws;
  size_t o = 0;
  auto take = [&](size_t bytes) { char* r = wsp + o; o = (o + bytes + 255) & ~(size_t)255; return r; };
  short* wq   = (short*)take(1536ul * 768 * 2);
  short* wm   = (short*)take(768ul * 512 * 2);
  short* wf1  = (short*)take(2048ul * 768 * 2);
  short* wf2  = (short*)take(768ul * 2048 * 2);
  short* wcv  = (short*)take(768ul * 256 * 2);
  float* t    = (float*)take(4100ul * 768 * 4);
  char*  hO   = take(4352ul * 768 * 2);              // h bf16 OR O bf16 (rows padded)
  short* qkv  = (short*)take(4ul * 1025 * 1536 * 2);
  char*  fV   = take(4352ul * 2048 * 2);             // f (padded) OR (im2col + tok)
  take(2ul << 20);                                   // slack for tile over-reads

  short* h   = (short*)hO;
  short* O   = (short*)hO;
  short* f   = (short*)fV;
  short* imc = (short*)fV;
  short* tok = (short*)(fV + 4096ul * 256 * 2);

  dim3 blk(256);

  // ---- patch embed ----
  cvt_k<<<768, blk, 0, stream>>>(conv_w, wcv, 768 * 256);
  im2col_k<<<4096, blk, 0, stream>>>(x, imc);
  gemm_t<64><<<dim3(12, 64), blk, 0, stream>>>(imc, wcv, tok, conv_b,
      4096, 768, 256, 256, 256, 768, 1 | 8);
  assemble_k<<<12300, blk, 0, stream>>>(tok, cls, pos, t);

  for (int i = 0; i < 12; ++i) {
    tconv4_k<<<4608, blk, 0, stream>>>(
        qkv_w + (long)i * 768 * 1536, merge_w + (long)i * 512 * 768,
        ffn_w1 + (long)i * 768 * 2048, ffn_w2 + (long)i * 2048 * 768,
        wq, wm, wf1, wf2);

    // h = LN1(t)
    ln_k<short><<<4100, blk, 0, stream>>>(t, ln1_s + i * 768, ln1_b + i * 768, h, 4100);
    // qkv = h @ qkv_w
    gemm128<<<dim3(12, 33), blk, 0, stream>>>(h, wq, qkv, nullptr,
        4100, 1536, 768, 768, 768, 1536, 8);
    // fused attention -> O
    flash_k<<<544, blk, 0, stream>>>(qkv, O);
    // t += O @ merge_w + merge_b
    gemm_t<64><<<dim3(12, 65), blk, 0, stream>>>(O, wm, t, merge_b + i * 768,
        4100, 768, 512, 512, 512, 768, 1 | 4);
    // h = LN2(t)
    ln_k<short><<<4100, blk, 0, stream>>>(t, ln2_s + i * 768, ln2_b + i * 768, h, 4100);
    // f = GELU(h @ ffn_w1 + b1)
    gemm128<<<dim3(16, 33), blk, 0, stream>>>(h, wf1, f, ffn_b1 + i * 2048,
        4100, 2048, 768, 768, 768, 2048, 1 | 2 | 8);
    // t += f @ ffn_w2 + b2
    gemm_t<64><<<dim3(12, 65), blk, 0, stream>>>(f, wf2, t, ffn_b2 + i * 768,
        4100, 768, 2048, 2048, 2048, 768, 1 | 4);
  }
  ln_k<float><<<4100, blk, 0, stream>>>(t, lnf_s, lnf_b, (float*)d_out, 4100);
}

// Round 9
// 2296.973 us; speedup vs baseline: 1.0638x; 1.0638x over previous
//
#include <hip/hip_runtime.h>

#define DEV __device__ __forceinline__

typedef short s8v __attribute__((ext_vector_type(8)));
typedef float f4v __attribute__((ext_vector_type(4)));

DEV short f2bf(float f) {
  unsigned u = __float_as_uint(f);
  u += 0x7FFFu + ((u >> 16) & 1u);
  return (short)(u >> 16);
}
DEV short f2bf_fast(float f) {           // round-to-nearest, no tie-to-even (P in (0,1])
  return (short)((__float_as_uint(f) + 0x8000u) >> 16);
}
DEV float bf2f(short s) { return __uint_as_float(((unsigned)(unsigned short)s) << 16); }

DEV void gld_lds16(const short* g, short* l) {
  __builtin_amdgcn_global_load_lds(
      (const __attribute__((address_space(1))) void*)g,
      (__attribute__((address_space(3))) void*)l, 16, 0, 0);
}

// XCD-bijective swizzle (m204)
DEV int xcd_swz(int id, int nwg) {
  int q8 = nwg >> 3, r8 = nwg & 7, xcd = id & 7, off = id >> 3;
  return (xcd < r8) ? (xcd * (q8 + 1) + off) : (r8 * (q8 + 1) + (xcd - r8) * q8 + off);
}

// ================= 64xBN tile bf16 BT GEMM, dbuf + chunk-swizzle =================
// BN=128: waves 1x4 (64x32 each). BN=64: waves 2x2 (32x32).
// flags: 1=+bias[col], 2=exact GELU, 4=accumulate into fp32 C, 8=bf16 out
template<int BN>
__global__ __launch_bounds__(256) void gemm_t(
    const short* __restrict__ A, const short* __restrict__ B, void* __restrict__ Cv,
    const float* __restrict__ bias,
    int M, int N, int K, int lda, int ldb, int ldc, int flags)
{
  constexpr int BPASS = BN / 32;
  constexpr int MI = (BN == 128) ? 4 : 2;
  __shared__ __align__(16) short As[2][64 * 64];
  __shared__ __align__(16) short Bs[2][BN * 64];
  int nwg = gridDim.x * gridDim.y;
  int idl = blockIdx.y * gridDim.x + blockIdx.x;
  int swz = xcd_swz(idl, nwg);
  int bx = swz % gridDim.x, by = swz / gridDim.x;
  int m0 = by * 64, n0 = bx * BN;
  int tid = threadIdx.x, lane = tid & 63, w = tid >> 6;
  int lr = lane & 15, kg = lane >> 4;
  int wrb = (BN == 128) ? 0 : (w >> 1) * 32;
  int wcb = (BN == 128) ? w * 32 : (w & 1) * 32;
  f4v acc[MI][2] = {};
  int NT = K >> 6;

#define STAGE(bufi, k0)                                                   \
  {                                                                       \
    _Pragma("unroll")                                                     \
    for (int p = 0; p < 2; ++p) {                                         \
      int ch = p * 256 + w * 64 + lane;                                   \
      int row = ch >> 3, c = (ch & 7) ^ (row & 7);                        \
      gld_lds16(A + (long)(m0 + row) * lda + (k0) + c * 8,                \
                &As[bufi][(p * 256 + w * 64) * 8]);                       \
    }                                                                     \
    _Pragma("unroll")                                                     \
    for (int p = 0; p < BPASS; ++p) {                                     \
      int ch = p * 256 + w * 64 + lane;                                   \
      int row = ch >> 3, c = (ch & 7) ^ (row & 7);                        \
      gld_lds16(B + (long)(n0 + row) * ldb + (k0) + c * 8,                \
                &Bs[bufi][(p * 256 + w * 64) * 8]);                       \
    }                                                                     \
  }

  STAGE(0, 0)
  for (int t = 0; t < NT; ++t) {
    int buf = t & 1;
    if (t + 1 < NT) {
      STAGE(buf ^ 1, (t + 1) * 64)
      if constexpr (BN == 128)
        asm volatile("s_waitcnt vmcnt(6)" ::: "memory");   // retire tile-t loads only
      else
        asm volatile("s_waitcnt vmcnt(4)" ::: "memory");
    } else {
      asm volatile("s_waitcnt vmcnt(0)" ::: "memory");
    }
    __builtin_amdgcn_s_barrier();
    #pragma unroll
    for (int ks = 0; ks < 2; ++ks) {
      s8v av[MI], bv[2];
      #pragma unroll
      for (int mi = 0; mi < MI; ++mi) {
        int row = wrb + mi * 16 + lr;
        int sl = (ks * 4 + kg) ^ (row & 7);
        av[mi] = *(const s8v*)&As[buf][row * 64 + sl * 8];
      }
      #pragma unroll
      for (int ni = 0; ni < 2; ++ni) {
        int row = wcb + ni * 16 + lr;
        int sl = (ks * 4 + kg) ^ (row & 7);
        bv[ni] = *(const s8v*)&Bs[buf][row * 64 + sl * 8];
      }
      #pragma unroll
      for (int mi = 0; mi < MI; ++mi)
        #pragma unroll
        for (int ni = 0; ni < 2; ++ni)
          acc[mi][ni] = __builtin_amdgcn_mfma_f32_16x16x32_bf16(av[mi], bv[ni], acc[mi][ni], 0, 0, 0);
    }
    asm volatile("s_waitcnt lgkmcnt(0)" ::: "memory");
    __builtin_amdgcn_s_barrier();
  }
#undef STAGE

  float* Cf = (float*)Cv;
  short* Cb = (short*)Cv;
  #pragma unroll
  for (int mi = 0; mi < MI; ++mi)
    #pragma unroll
    for (int ni = 0; ni < 2; ++ni) {
      int col = n0 + wcb + ni * 16 + lr;
      float bvv = (flags & 1) ? bias[col] : 0.f;
      #pragma unroll
      for (int j = 0; j < 4; ++j) {
        int row = m0 + wrb + mi * 16 + kg * 4 + j;
        if (row >= M) continue;
        float v = acc[mi][ni][j] + bvv;
        if (flags & 2) v = 0.5f * v * (1.f + erff(v * 0.70710678118f));
        long ci = (long)row * ldc + col;
        if (flags & 8) Cb[ci] = f2bf(v);
        else { if (flags & 4) v += Cf[ci]; Cf[ci] = v; }
      }
    }
}

// ---------------- fused flash attention (dbuf K/V, setprio, exp2 softmax) ----------------
// qkv: [4][1025][1536] bf16 (Q +0, K +64, V +128 per head zh*192)
// O:   [4][1025][512]  bf16
__global__ __launch_bounds__(256) void flash_k(
    const short* __restrict__ qkv, short* __restrict__ O)
{
  int swz = xcd_swz(blockIdx.x, 544);
  int z = swz / 17, qt = swz - z * 17;
  int zb = z >> 3, zh = z & 7;
  const short* base = qkv + (long)zb * 1025 * 1536 + zh * 192;
  const short* Qg = base;
  const short* Kg = base + 64;
  const short* Vg = base + 128;
  int q0 = qt * 64;
  int tid = threadIdx.x, lane = tid & 63, w = tid >> 6;
  int lr = lane & 15, kg = lane >> 4;

  __shared__ __align__(16) short QPs[64][72];   // Q in prologue; per-wave P after
  __shared__ __align__(16) short Ks[2][64 * 64];
  __shared__ __align__(16) short Vt[2][64][72];

  for (int s = tid; s < 512; s += 256) {
    int row = s >> 3, ch = s & 7;
    s8v v = {};
    if (q0 + row < 1025) v = *(const s8v*)(Qg + (long)(q0 + row) * 1536 + ch * 8);
    *(s8v*)&QPs[row][ch * 8] = v;
  }
  __syncthreads();
  s8v aq[2];
  aq[0] = *(const s8v*)&QPs[w * 16 + lr][kg * 8];
  aq[1] = *(const s8v*)&QPs[w * 16 + lr][32 + kg * 8];

#define STAGE_K(bufi, kv0)                                                 \
  {                                                                        \
    int s0 = w * 128;                                                      \
    _Pragma("unroll")                                                      \
    for (int i = 0; i < 2; ++i) {                                          \
      int s = s0 + i * 64 + lane;                                          \
      int row = s >> 3, c = (s & 7) ^ (row & 7);                           \
      gld_lds16(Kg + (long)((kv0) + row) * 1536 + c * 8,                   \
                &Ks[bufi][(s0 + i * 64) * 8]);                             \
    }                                                                      \
  }

  f4v acc[4] = {};
  float m_run[4], l_run[4];
  #pragma unroll
  for (int j = 0; j < 4; ++j) { m_run[j] = -3.0e38f; l_run[j] = 0.f; }
  const float C2 = 0.18033688011112042f;   // 0.125 * log2(e): exp(x/8) = exp2(x*C2)

  // prologue: tile 0
  STAGE_K(0, 0)
  #pragma unroll
  for (int p = 0; p < 2; ++p) {
    int s = p * 256 + tid;
    int key = s & 63, ch = s >> 6;
    s8v v = *(const s8v*)(Vg + (long)key * 1536 + ch * 8);
    #pragma unroll
    for (int j = 0; j < 8; ++j) Vt[0][ch * 8 + j][key] = v[j];
  }
  asm volatile("s_waitcnt vmcnt(0)" ::: "memory");
  asm volatile("s_waitcnt lgkmcnt(0)" ::: "memory");
  __builtin_amdgcn_s_barrier();

  for (int kt = 0; kt < 17; ++kt) {
    int cur = kt & 1;
    int kv0 = kt * 64;
    s8v vreg[2];
    int vok[2];
    if (kt < 16) {
      STAGE_K(cur ^ 1, kv0 + 64)
      #pragma unroll
      for (int p = 0; p < 2; ++p) {
        int s = p * 256 + tid;
        int key = (s & 63) + kv0 + 64, ch = s >> 6;
        vok[p] = key < 1025;
        vreg[p] = vok[p] ? *(const s8v*)(Vg + (long)key * 1536 + ch * 8) : s8v{};
      }
    }

    // S = Q K^T
    f4v sa[4] = {};
    __builtin_amdgcn_s_setprio(1);
    #pragma unroll
    for (int ni = 0; ni < 4; ++ni) {
      int row = ni * 16 + lr;
      #pragma unroll
      for (int ks = 0; ks < 2; ++ks) {
        int c = (ks * 4 + kg) ^ (row & 7);
        s8v bk = *(const s8v*)&Ks[cur][row * 64 + c * 8];
        sa[ni] = __builtin_amdgcn_mfma_f32_16x16x32_bf16(aq[ks], bk, sa[ni], 0, 0, 0);
      }
    }
    __builtin_amdgcn_s_setprio(0);
    // online softmax in exp2 domain; mask only the last tile (wave-uniform branch)
    float sv[4][4], pv[4][4], tm[4], ts[4];
    #pragma unroll
    for (int j = 0; j < 4; ++j) tm[j] = -3.0e38f;
    if (kt != 16) {
      #pragma unroll
      for (int ni = 0; ni < 4; ++ni)
        #pragma unroll
        for (int j = 0; j < 4; ++j) {
          float s = sa[ni][j] * C2;
          sv[ni][j] = s;
          tm[j] = fmaxf(tm[j], s);
        }
    } else {
      #pragma unroll
      for (int ni = 0; ni < 4; ++ni) {
        bool valid = (kv0 + ni * 16 + lr) < 1025;
        #pragma unroll
        for (int j = 0; j < 4; ++j) {
          float s = valid ? sa[ni][j] * C2 : -3.0e38f;
          sv[ni][j] = s;
          tm[j] = fmaxf(tm[j], s);
        }
      }
    }
    #pragma unroll
    for (int o = 1; o < 16; o <<= 1)
      #pragma unroll
      for (int j = 0; j < 4; ++j) tm[j] = fmaxf(tm[j], __shfl_xor(tm[j], o));
    float scale[4], m_new[4];
    #pragma unroll
    for (int j = 0; j < 4; ++j) {
      m_new[j] = fmaxf(m_run[j], tm[j]);
      scale[j] = exp2f(m_run[j] - m_new[j]);
      m_run[j] = m_new[j];
      ts[j] = 0.f;
    }
    #pragma unroll
    for (int ni = 0; ni < 4; ++ni)
      #pragma unroll
      for (int j = 0; j < 4; ++j) {
        float p = exp2f(sv[ni][j] - m_new[j]);
        pv[ni][j] = p;
        ts[j] += p;
      }
    #pragma unroll
    for (int o = 1; o < 16; o <<= 1)
      #pragma unroll
      for (int j = 0; j < 4; ++j) ts[j] += __shfl_xor(ts[j], o);
    #pragma unroll
    for (int j = 0; j < 4; ++j) l_run[j] = l_run[j] * scale[j] + ts[j];
    #pragma unroll
    for (int ni = 0; ni < 4; ++ni)
      #pragma unroll
      for (int j = 0; j < 4; ++j) acc[ni][j] *= scale[j];

    // write next tile's V (reg loads auto-waited; hides under softmax)
    if (kt < 16) {
      #pragma unroll
      for (int p = 0; p < 2; ++p) {
        int s = p * 256 + tid;
        int key = s & 63, ch = s >> 6;
        s8v v = vok[p] ? vreg[p] : s8v{};
        #pragma unroll
        for (int j = 0; j < 8; ++j) Vt[cur ^ 1][ch * 8 + j][key] = v[j];
      }
    }

    // P -> per-wave LDS slice
    #pragma unroll
    for (int ni = 0; ni < 4; ++ni)
      #pragma unroll
      for (int j = 0; j < 4; ++j)
        QPs[w * 16 + kg * 4 + j][ni * 16 + lr] = f2bf_fast(pv[ni][j]);
    asm volatile("s_waitcnt lgkmcnt(0)" ::: "memory");
    // O += P V
    s8v ap[2];
    ap[0] = *(const s8v*)&QPs[w * 16 + lr][kg * 8];
    ap[1] = *(const s8v*)&QPs[w * 16 + lr][32 + kg * 8];
    __builtin_amdgcn_s_setprio(1);
    #pragma unroll
    for (int ni = 0; ni < 4; ++ni) {
      #pragma unroll
      for (int ks = 0; ks < 2; ++ks) {
        s8v bvv = *(const s8v*)&Vt[cur][ni * 16 + lr][ks * 32 + kg * 8];
        acc[ni] = __builtin_amdgcn_mfma_f32_16x16x32_bf16(ap[ks], bvv, acc[ni], 0, 0, 0);
      }
    }
    __builtin_amdgcn_s_setprio(0);
    asm volatile("s_waitcnt lgkmcnt(0)" ::: "memory");
    asm volatile("s_waitcnt vmcnt(0)" ::: "memory");
    __builtin_amdgcn_s_barrier();
  }
#undef STAGE_K

  float inv[4];
  #pragma unroll
  for (int j = 0; j < 4; ++j) inv[j] = 1.f / l_run[j];
  #pragma unroll
  for (int ni = 0; ni < 4; ++ni)
    #pragma unroll
    for (int j = 0; j < 4; ++j) {
      int row = q0 + w * 16 + kg * 4 + j;
      if (row < 1025)
        O[((long)(zb * 1025 + row)) * 512 + zh * 64 + ni * 16 + lr] = f2bf(acc[ni][j] * inv[j]);
    }
}

// ---------------- fused per-layer weight transpose+convert ----------------
DEV void tconv_body(const float* w, short* wt, int K, int N, int bx, int by, int tid)
{
  __shared__ float tile[32][33];
  int n0 = bx * 32, k0 = by * 32;
  int tx = tid & 31, ty = tid >> 5;
  #pragma unroll
  for (int j = 0; j < 4; ++j)
    tile[ty + j * 8][tx] = w[(long)(k0 + ty + j * 8) * N + n0 + tx];
  __syncthreads();
  #pragma unroll
  for (int j = 0; j < 4; ++j)
    wt[(long)(n0 + ty + j * 8) * K + k0 + tx] = f2bf(tile[tx][ty + j * 8]);
}

__global__ __launch_bounds__(256) void tconv4_k(
    const float* __restrict__ sq, const float* __restrict__ sm,
    const float* __restrict__ sf1, const float* __restrict__ sf2,
    short* __restrict__ dq, short* __restrict__ dm,
    short* __restrict__ df1, short* __restrict__ df2)
{
  int id = blockIdx.x, tid = threadIdx.x;
  if (id < 1152)       tconv_body(sq,  dq,  768, 1536, id % 48,          id / 48,          tid);
  else if (id < 1536)  tconv_body(sm,  dm,  512, 768,  (id - 1152) % 24, (id - 1152) / 24, tid);
  else if (id < 3072)  tconv_body(sf1, df1, 768, 2048, (id - 1536) % 64, (id - 1536) / 64, tid);
  else                 tconv_body(sf2, df2, 2048, 768, (id - 3072) % 24, (id - 3072) / 24, tid);
}

// ---------------- elementwise fp32 -> bf16 ----------------
__global__ __launch_bounds__(256) void cvt_k(const float* __restrict__ in,
    short* __restrict__ out, int n)
{
  int i = blockIdx.x * 256 + threadIdx.x;
  if (i < n) out[i] = f2bf(in[i]);
}

// ---------------- LayerNorm D=768 ----------------
DEV void st_ln(float* p, float v) { *p = v; }
DEV void st_ln(short* p, float v) { *p = f2bf(v); }

template<typename OT>
__global__ __launch_bounds__(256) void ln_k(const float* __restrict__ x,
    const float* __restrict__ g, const float* __restrict__ b,
    OT* __restrict__ y, int rows)
{
  int row = blockIdx.x;
  if (row >= rows) return;
  const float* xr = x + (long)row * 768;
  OT* yr = y + (long)row * 768;
  int t = threadIdx.x;
  float v0 = xr[t], v1 = xr[t + 256], v2 = xr[t + 512];
  float s = v0 + v1 + v2, s2 = v0 * v0 + v1 * v1 + v2 * v2;
  #pragma unroll
  for (int o = 32; o > 0; o >>= 1) { s += __shfl_down(s, o); s2 += __shfl_down(s2, o); }
  __shared__ float as_[4], as2_[4];
  if ((t & 63) == 0) { as_[t >> 6] = s; as2_[t >> 6] = s2; }
  __syncthreads();
  s = as_[0] + as_[1] + as_[2] + as_[3];
  s2 = as2_[0] + as2_[1] + as2_[2] + as2_[3];
  float mean = s * (1.f / 768.f);
  float var = s2 * (1.f / 768.f) - mean * mean;
  float r = rsqrtf(var + 1e-5f);
  st_ln(&yr[t],       (v0 - mean) * r * g[t]       + b[t]);
  st_ln(&yr[t + 256], (v1 - mean) * r * g[t + 256] + b[t + 256]);
  st_ln(&yr[t + 512], (v2 - mean) * r * g[t + 512] + b[t + 512]);
}

// ---------------- patch extraction ----------------
__global__ __launch_bounds__(256) void im2col_k(const float* __restrict__ x,
    short* __restrict__ A)
{
  int i = blockIdx.x * 256 + threadIdx.x;
  int k = i & 255, row = i >> 8;
  int px = k & 15, py = k >> 4;
  int gx = row & 31, gy = (row >> 5) & 31, b = row >> 10;
  A[i] = f2bf(x[((long)(b * 512) + gy * 16 + py) * 512 + gx * 16 + px]);
}

// ---------------- t = concat(cls, tok) + pos ----------------
__global__ __launch_bounds__(256) void assemble_k(const short* __restrict__ tok,
    const float* __restrict__ cls, const float* __restrict__ pos, float* __restrict__ t)
{
  int i = blockIdx.x * 256 + threadIdx.x;
  int d = i % 768; int rn = i / 768; int n = rn % 1025; int b = rn / 1025;
  float v = (n == 0) ? cls[d] : bf2f(tok[((long)(b * 1024 + n - 1)) * 768 + d]);
  t[i] = v + pos[n * 768 + d];
}

extern "C" void kernel_launch(void* const* d_in, const int* in_sizes, int n_in,
                              void* d_out, int out_size, void* d_ws, size_t ws_size,
                              hipStream_t stream)
{
  const float* x       = (const float*)d_in[0];
  const float* conv_w  = (const float*)d_in[1];
  const float* conv_b  = (const float*)d_in[2];
  const float* cls     = (const float*)d_in[3];
  const float* pos     = (const float*)d_in[4];
  const float* qkv_w   = (const float*)d_in[5];
  const float* merge_w = (const float*)d_in[6];
  const float* merge_b = (const float*)d_in[7];
  const float* ln1_s   = (const float*)d_in[8];
  const float* ln1_b   = (const float*)d_in[9];
  const float* ln2_s   = (const float*)d_in[10];
  const float* ln2_b   = (const float*)d_in[11];
  const float* ffn_w1  = (const float*)d_in[12];
  const float* ffn_b1  = (const float*)d_in[13];
  const float* ffn_w2  = (const float*)d_in[14];
  const float* ffn_b2  = (const float*)d_in[15];
  const float* lnf_s   = (const float*)d_in[16];
  const float* lnf_b   = (const float*)d_in[17];

  char* wsp = (char*)d_ws;
  size_t o = 0;
  auto take = [&](size_t bytes) { char* r = wsp + o; o = (o + bytes + 255) & ~(size_t)255; return r; };
  short* wq   = (short*)take(1536ul * 768 * 2);
  short* wm   = (short*)take(768ul * 512 * 2);
  short* wf1  = (short*)take(2048ul * 768 * 2);
  short* wf2  = (short*)take(768ul * 2048 * 2);
  short* wcv  = (short*)take(768ul * 256 * 2);
  float* t    = (float*)take(4100ul * 768 * 4);
  char*  hO   = take(4352ul * 768 * 2);              // h bf16 OR O bf16 (rows padded)
  short* qkv  = (short*)take(4ul * 1025 * 1536 * 2);
  char*  fV   = take(4352ul * 2048 * 2);             // f (padded) OR (im2col + tok)
  take(2ul << 20);                                   // slack for tile over-reads

  short* h   = (short*)hO;
  short* O   = (short*)hO;
  short* f   = (short*)fV;
  short* imc = (short*)fV;
  short* tok = (short*)(fV + 4096ul * 256 * 2);

  dim3 blk(256);

  // ---- patch embed ----
  cvt_k<<<768, blk, 0, stream>>>(conv_w, wcv, 768 * 256);
  im2col_k<<<4096, blk, 0, stream>>>(x, imc);
  gemm_t<64><<<dim3(12, 64), blk, 0, stream>>>(imc, wcv, tok, conv_b,
      4096, 768, 256, 256, 256, 768, 1 | 8);
  assemble_k<<<12300, blk, 0, stream>>>(tok, cls, pos, t);

  for (int i = 0; i < 12; ++i) {
    tconv4_k<<<4608, blk, 0, stream>>>(
        qkv_w + (long)i * 768 * 1536, merge_w + (long)i * 512 * 768,
        ffn_w1 + (long)i * 768 * 2048, ffn_w2 + (long)i * 2048 * 768,
        wq, wm, wf1, wf2);

    // h = LN1(t)
    ln_k<short><<<4100, blk, 0, stream>>>(t, ln1_s + i * 768, ln1_b + i * 768, h, 4100);
    // qkv = h @ qkv_w
    gemm_t<128><<<dim3(12, 65), blk, 0, stream>>>(h, wq, qkv, nullptr,
        4100, 1536, 768, 768, 768, 1536, 8);
    // fused attention -> O
    flash_k<<<544, blk, 0, stream>>>(qkv, O);
    // t += O @ merge_w + merge_b
    gemm_t<64><<<dim3(12, 65), blk, 0, stream>>>(O, wm, t, merge_b + i * 768,
        4100, 768, 512, 512, 512, 768, 1 | 4);
    // h = LN2(t)
    ln_k<short><<<4100, blk, 0, stream>>>(t, ln2_s + i * 768, ln2_b + i * 768, h, 4100);
    // f = GELU(h @ ffn_w1 + b1)
    gemm_t<128><<<dim3(16, 65), blk, 0, stream>>>(h, wf1, f, ffn_b1 + i * 2048,
        4100, 2048, 768, 768, 768, 2048, 1 | 2 | 8);
    // t += f @ ffn_w2 + b2
    gemm_t<64><<<dim3(12, 65), blk, 0, stream>>>(f, wf2, t, ffn_b2 + i * 768,
        4100, 768, 2048, 2048, 2048, 768, 1 | 4);
  }
  ln_k<float><<<4100, blk, 0, stream>>>(t, lnf_s, lnf_b, (float*)d_out, 4100);
}

// Round 10
// 2133.552 us; speedup vs baseline: 1.1452x; 1.0766x over previous
//
#include <hip/hip_runtime.h>

#define DEV __device__ __forceinline__

typedef short s8v __attribute__((ext_vector_type(8)));
typedef float f4v __attribute__((ext_vector_type(4)));

DEV short f2bf(float f) {
  unsigned u = __float_as_uint(f);
  u += 0x7FFFu + ((u >> 16) & 1u);
  return (short)(u >> 16);
}
DEV short f2bf_fast(float f) {           // round-to-nearest, no tie-to-even (P in [0,1])
  return (short)((__float_as_uint(f) + 0x8000u) >> 16);
}
DEV float bf2f(short s) { return __uint_as_float(((unsigned)(unsigned short)s) << 16); }

DEV void gld_lds16(const short* g, short* l) {
  __builtin_amdgcn_global_load_lds(
      (const __attribute__((address_space(1))) void*)g,
      (__attribute__((address_space(3))) void*)l, 16, 0, 0);
}

// XCD-bijective swizzle (m204)
DEV int xcd_swz(int id, int nwg) {
  int q8 = nwg >> 3, r8 = nwg & 7, xcd = id & 7, off = id >> 3;
  return (xcd < r8) ? (xcd * (q8 + 1) + off) : (r8 * (q8 + 1) + (xcd - r8) * q8 + off);
}

// ================= 64xBN tile bf16 BT GEMM, dbuf + chunk-swizzle =================
// BN=128: waves 1x4 (64x32 each). BN=64: waves 2x2 (32x32).
// flags: 1=+bias[col], 2=exact GELU, 4=accumulate into fp32 C, 8=bf16 out
template<int BN>
__global__ __launch_bounds__(256) void gemm_t(
    const short* __restrict__ A, const short* __restrict__ B, void* __restrict__ Cv,
    const float* __restrict__ bias,
    int M, int N, int K, int lda, int ldb, int ldc, int flags)
{
  constexpr int BPASS = BN / 32;
  constexpr int MI = (BN == 128) ? 4 : 2;
  __shared__ __align__(16) short As[2][64 * 64];
  __shared__ __align__(16) short Bs[2][BN * 64];
  int nwg = gridDim.x * gridDim.y;
  int idl = blockIdx.y * gridDim.x + blockIdx.x;
  int swz = xcd_swz(idl, nwg);
  int bx = swz % gridDim.x, by = swz / gridDim.x;
  int m0 = by * 64, n0 = bx * BN;
  int tid = threadIdx.x, lane = tid & 63, w = tid >> 6;
  int lr = lane & 15, kg = lane >> 4;
  int wrb = (BN == 128) ? 0 : (w >> 1) * 32;
  int wcb = (BN == 128) ? w * 32 : (w & 1) * 32;
  f4v acc[MI][2] = {};
  int NT = K >> 6;

#define STAGE(bufi, k0)                                                   \
  {                                                                       \
    _Pragma("unroll")                                                     \
    for (int p = 0; p < 2; ++p) {                                         \
      int ch = p * 256 + w * 64 + lane;                                   \
      int row = ch >> 3, c = (ch & 7) ^ (row & 7);                        \
      gld_lds16(A + (long)(m0 + row) * lda + (k0) + c * 8,                \
                &As[bufi][(p * 256 + w * 64) * 8]);                       \
    }                                                                     \
    _Pragma("unroll")                                                     \
    for (int p = 0; p < BPASS; ++p) {                                     \
      int ch = p * 256 + w * 64 + lane;                                   \
      int row = ch >> 3, c = (ch & 7) ^ (row & 7);                        \
      gld_lds16(B + (long)(n0 + row) * ldb + (k0) + c * 8,                \
                &Bs[bufi][(p * 256 + w * 64) * 8]);                       \
    }                                                                     \
  }

  STAGE(0, 0)
  for (int t = 0; t < NT; ++t) {
    int buf = t & 1;
    if (t + 1 < NT) {
      STAGE(buf ^ 1, (t + 1) * 64)
      if constexpr (BN == 128)
        asm volatile("s_waitcnt vmcnt(6)" ::: "memory");   // retire tile-t loads only
      else
        asm volatile("s_waitcnt vmcnt(4)" ::: "memory");
    } else {
      asm volatile("s_waitcnt vmcnt(0)" ::: "memory");
    }
    __builtin_amdgcn_s_barrier();
    #pragma unroll
    for (int ks = 0; ks < 2; ++ks) {
      s8v av[MI], bv[2];
      #pragma unroll
      for (int mi = 0; mi < MI; ++mi) {
        int row = wrb + mi * 16 + lr;
        int sl = (ks * 4 + kg) ^ (row & 7);
        av[mi] = *(const s8v*)&As[buf][row * 64 + sl * 8];
      }
      #pragma unroll
      for (int ni = 0; ni < 2; ++ni) {
        int row = wcb + ni * 16 + lr;
        int sl = (ks * 4 + kg) ^ (row & 7);
        bv[ni] = *(const s8v*)&Bs[buf][row * 64 + sl * 8];
      }
      #pragma unroll
      for (int mi = 0; mi < MI; ++mi)
        #pragma unroll
        for (int ni = 0; ni < 2; ++ni)
          acc[mi][ni] = __builtin_amdgcn_mfma_f32_16x16x32_bf16(av[mi], bv[ni], acc[mi][ni], 0, 0, 0);
    }
    asm volatile("s_waitcnt lgkmcnt(0)" ::: "memory");
    __builtin_amdgcn_s_barrier();
  }
#undef STAGE

  float* Cf = (float*)Cv;
  short* Cb = (short*)Cv;
  #pragma unroll
  for (int mi = 0; mi < MI; ++mi)
    #pragma unroll
    for (int ni = 0; ni < 2; ++ni) {
      int col = n0 + wcb + ni * 16 + lr;
      float bvv = (flags & 1) ? bias[col] : 0.f;
      #pragma unroll
      for (int j = 0; j < 4; ++j) {
        int row = m0 + wrb + mi * 16 + kg * 4 + j;
        if (row >= M) continue;
        float v = acc[mi][ni][j] + bvv;
        if (flags & 2) v = 0.5f * v * (1.f + erff(v * 0.70710678118f));
        long ci = (long)row * ldc + col;
        if (flags & 8) Cb[ci] = f2bf(v);
        else { if (flags & 4) v += Cf[ci]; Cf[ci] = v; }
      }
    }
}

// ---------------- fused flash attention, swapped-QK^T (P in registers) ----------------
// qkv: [4][1025][1536] bf16 (Q +0, K +64, V +128 per head zh*192)
// O:   [4][1025][512]  bf16
// S computed as mfma(K, Q): lane (lr,kg) holds S[key=ni*16+kg*4+jj][q=lr]
// -> per-lane softmax (q = lr), P redistributed to PV A-frag via 8 shfl.
__global__ __launch_bounds__(256) void flash_k(
    const short* __restrict__ qkv, short* __restrict__ O)
{
  int swz = xcd_swz(blockIdx.x, 544);
  int z = swz / 17, qt = swz - z * 17;
  int zb = z >> 3, zh = z & 7;
  const short* base = qkv + (long)zb * 1025 * 1536 + zh * 192;
  const short* Qg = base;
  const short* Kg = base + 64;
  const short* Vg = base + 128;
  int q0 = qt * 64;
  int tid = threadIdx.x, lane = tid & 63, w = tid >> 6;
  int lr = lane & 15, kg = lane >> 4;

  __shared__ __align__(16) short Ks[2][64 * 64];
  __shared__ __align__(16) short Vt[2][64][72];

  // Q direct to registers (per-lane 16B loads; q0+... over-read lands in ws slack)
  s8v aq[2];
  {
    long qrow = q0 + w * 16 + lr;
    aq[0] = *(const s8v*)(Qg + qrow * 1536 + kg * 8);
    aq[1] = *(const s8v*)(Qg + qrow * 1536 + 32 + kg * 8);
  }

#define STAGE_K(bufi, kv0)                                                 \
  {                                                                        \
    int s0 = w * 128;                                                      \
    _Pragma("unroll")                                                      \
    for (int i = 0; i < 2; ++i) {                                          \
      int s = s0 + i * 64 + lane;                                          \
      int row = s >> 3, c = (s & 7) ^ (row & 7);                           \
      gld_lds16(Kg + (long)((kv0) + row) * 1536 + c * 8,                   \
                &Ks[bufi][(s0 + i * 64) * 8]);                             \
    }                                                                      \
  }

  f4v acc[4] = {};
  float m_run = -3.0e38f, l_run = 0.f;
  const float C2 = 0.18033688011112042f;   // 0.125 * log2(e)

  // prologue: tile 0 (keys 0..63 always valid)
  STAGE_K(0, 0)
  #pragma unroll
  for (int p = 0; p < 2; ++p) {
    int s = p * 256 + tid;
    int key = s & 63, ch = s >> 6;
    s8v v = *(const s8v*)(Vg + (long)key * 1536 + ch * 8);
    #pragma unroll
    for (int j = 0; j < 8; ++j) Vt[0][ch * 8 + j][key] = v[j];
  }
  asm volatile("s_waitcnt vmcnt(0)" ::: "memory");
  asm volatile("s_waitcnt lgkmcnt(0)" ::: "memory");
  __builtin_amdgcn_s_barrier();

  for (int kt = 0; kt < 17; ++kt) {
    int cur = kt & 1;
    int kv0 = kt * 64;
    s8v vreg[2];
    int vok[2];
    if (kt < 16) {
      STAGE_K(cur ^ 1, kv0 + 64)
      #pragma unroll
      for (int p = 0; p < 2; ++p) {
        int s = p * 256 + tid;
        int key = (s & 63) + kv0 + 64, ch = s >> 6;
        vok[p] = key < 1025;
        vreg[p] = vok[p] ? *(const s8v*)(Vg + (long)key * 1536 + ch * 8) : s8v{};
      }
    }

    // S^T = K Q^T : A = K-frag (same reads as before), B = Q regs
    f4v sa[4] = {};
    __builtin_amdgcn_s_setprio(1);
    #pragma unroll
    for (int ni = 0; ni < 4; ++ni) {
      int row = ni * 16 + lr;
      #pragma unroll
      for (int ks = 0; ks < 2; ++ks) {
        int c = (ks * 4 + kg) ^ (row & 7);
        s8v kf = *(const s8v*)&Ks[cur][row * 64 + c * 8];
        sa[ni] = __builtin_amdgcn_mfma_f32_16x16x32_bf16(kf, aq[ks], sa[ni], 0, 0, 0);
      }
    }
    __builtin_amdgcn_s_setprio(0);

    // per-lane online softmax over keys (q = lr)
    float sv[4][4], pv[4][4];
    float tm = -3.0e38f;
    if (kt != 16) {
      #pragma unroll
      for (int ni = 0; ni < 4; ++ni)
        #pragma unroll
        for (int jj = 0; jj < 4; ++jj) {
          float s = sa[ni][jj] * C2;
          sv[ni][jj] = s;
          tm = fmaxf(tm, s);
        }
    } else {
      #pragma unroll
      for (int ni = 0; ni < 4; ++ni)
        #pragma unroll
        for (int jj = 0; jj < 4; ++jj) sv[ni][jj] = -3.0e38f;
      if (kg == 0) sv[0][0] = sa[0][0] * C2;   // only key 1024 valid
      tm = sv[0][0];
    }
    tm = fmaxf(tm, __shfl_xor(tm, 16));
    tm = fmaxf(tm, __shfl_xor(tm, 32));
    float m_new = fmaxf(m_run, tm);
    float scale = exp2f(m_run - m_new);
    m_run = m_new;
    float ts = 0.f;
    #pragma unroll
    for (int ni = 0; ni < 4; ++ni)
      #pragma unroll
      for (int jj = 0; jj < 4; ++jj) {
        float p = exp2f(sv[ni][jj] - m_new);
        pv[ni][jj] = p;
        ts += p;
      }
    ts += __shfl_xor(ts, 16);
    ts += __shfl_xor(ts, 32);
    l_run = l_run * scale + ts;

    // broadcast scale to the lanes holding acc rows q = kg*4+jj
    float scq[4];
    #pragma unroll
    for (int jj = 0; jj < 4; ++jj)
      scq[jj] = __shfl(scale, kg * 4 + jj + 16 * kg);
    #pragma unroll
    for (int ni = 0; ni < 4; ++ni)
      #pragma unroll
      for (int jj = 0; jj < 4; ++jj) acc[ni][jj] *= scq[jj];

    // write next tile's V (reg loads auto-waited; hides under softmax)
    if (kt < 16) {
      #pragma unroll
      for (int p = 0; p < 2; ++p) {
        int s = p * 256 + tid;
        int key = s & 63, ch = s >> 6;
        s8v v = vok[p] ? vreg[p] : s8v{};
        #pragma unroll
        for (int j = 0; j < 8; ++j) Vt[cur ^ 1][ch * 8 + j][key] = v[j];
      }
    }

    // P -> bf16 pairs, then register redistribution to PV A-frag (8 shfl)
    unsigned pr[4][2];
    #pragma unroll
    for (int ni = 0; ni < 4; ++ni)
      #pragma unroll
      for (int h = 0; h < 2; ++h) {
        unsigned lo = (unsigned)(unsigned short)f2bf_fast(pv[ni][2 * h]);
        unsigned hi = (unsigned)(unsigned short)f2bf_fast(pv[ni][2 * h + 1]);
        pr[ni][h] = lo | (hi << 16);
      }
    union PU { s8v v; unsigned u[4]; };
    PU apu[2];
    #pragma unroll
    for (int ks = 0; ks < 2; ++ks)
      #pragma unroll
      for (int t = 0; t < 4; ++t) {
        unsigned src = (kg & 2) ? pr[2 * ks + 1][t & 1] : pr[2 * ks][t & 1];
        apu[ks].u[t] = __shfl(src, lr + 16 * (2 * (kg & 1) + (t >> 1)));
      }

    // O += P V
    __builtin_amdgcn_s_setprio(1);
    #pragma unroll
    for (int ni = 0; ni < 4; ++ni) {
      #pragma unroll
      for (int ks = 0; ks < 2; ++ks) {
        s8v bvv = *(const s8v*)&Vt[cur][ni * 16 + lr][ks * 32 + kg * 8];
        acc[ni] = __builtin_amdgcn_mfma_f32_16x16x32_bf16(apu[ks].v, bvv, acc[ni], 0, 0, 0);
      }
    }
    __builtin_amdgcn_s_setprio(0);
    asm volatile("s_waitcnt lgkmcnt(0)" ::: "memory");   // V writes flushed before barrier
    asm volatile("s_waitcnt vmcnt(0)" ::: "memory");     // next-tile K gld landed
    __builtin_amdgcn_s_barrier();
  }
#undef STAGE_K

  // epilogue: per-lane l (q=lr) -> broadcast to acc-row lanes, normalize, write
  float linv = 1.f / l_run;
  float invq[4];
  #pragma unroll
  for (int jj = 0; jj < 4; ++jj)
    invq[jj] = __shfl(linv, kg * 4 + jj + 16 * kg);
  #pragma unroll
  for (int ni = 0; ni < 4; ++ni)
    #pragma unroll
    for (int jj = 0; jj < 4; ++jj) {
      int row = q0 + w * 16 + kg * 4 + jj;
      if (row < 1025)
        O[((long)(zb * 1025 + row)) * 512 + zh * 64 + ni * 16 + lr] = f2bf(acc[ni][jj] * invq[jj]);
    }
}

// ---------------- fused per-layer weight transpose+convert ----------------
DEV void tconv_body(const float* w, short* wt, int K, int N, int bx, int by, int tid)
{
  __shared__ float tile[32][33];
  int n0 = bx * 32, k0 = by * 32;
  int tx = tid & 31, ty = tid >> 5;
  #pragma unroll
  for (int j = 0; j < 4; ++j)
    tile[ty + j * 8][tx] = w[(long)(k0 + ty + j * 8) * N + n0 + tx];
  __syncthreads();
  #pragma unroll
  for (int j = 0; j < 4; ++j)
    wt[(long)(n0 + ty + j * 8) * K + k0 + tx] = f2bf(tile[tx][ty + j * 8]);
}

__global__ __launch_bounds__(256) void tconv4_k(
    const float* __restrict__ sq, const float* __restrict__ sm,
    const float* __restrict__ sf1, const float* __restrict__ sf2,
    short* __restrict__ dq, short* __restrict__ dm,
    short* __restrict__ df1, short* __restrict__ df2)
{
  int id = blockIdx.x, tid = threadIdx.x;
  if (id < 1152)       tconv_body(sq,  dq,  768, 1536, id % 48,          id / 48,          tid);
  else if (id < 1536)  tconv_body(sm,  dm,  512, 768,  (id - 1152) % 24, (id - 1152) / 24, tid);
  else if (id < 3072)  tconv_body(sf1, df1, 768, 2048, (id - 1536) % 64, (id - 1536) / 64, tid);
  else                 tconv_body(sf2, df2, 2048, 768, (id - 3072) % 24, (id - 3072) / 24, tid);
}

// ---------------- elementwise fp32 -> bf16 ----------------
__global__ __launch_bounds__(256) void cvt_k(const float* __restrict__ in,
    short* __restrict__ out, int n)
{
  int i = blockIdx.x * 256 + threadIdx.x;
  if (i < n) out[i] = f2bf(in[i]);
}

// ---------------- LayerNorm D=768 ----------------
DEV void st_ln(float* p, float v) { *p = v; }
DEV void st_ln(short* p, float v) { *p = f2bf(v); }

template<typename OT>
__global__ __launch_bounds__(256) void ln_k(const float* __restrict__ x,
    const float* __restrict__ g, const float* __restrict__ b,
    OT* __restrict__ y, int rows)
{
  int row = blockIdx.x;
  if (row >= rows) return;
  const float* xr = x + (long)row * 768;
  OT* yr = y + (long)row * 768;
  int t = threadIdx.x;
  float v0 = xr[t], v1 = xr[t + 256], v2 = xr[t + 512];
  float s = v0 + v1 + v2, s2 = v0 * v0 + v1 * v1 + v2 * v2;
  #pragma unroll
  for (int o = 32; o > 0; o >>= 1) { s += __shfl_down(s, o); s2 += __shfl_down(s2, o); }
  __shared__ float as_[4], as2_[4];
  if ((t & 63) == 0) { as_[t >> 6] = s; as2_[t >> 6] = s2; }
  __syncthreads();
  s = as_[0] + as_[1] + as_[2] + as_[3];
  s2 = as2_[0] + as2_[1] + as2_[2] + as2_[3];
  float mean = s * (1.f / 768.f);
  float var = s2 * (1.f / 768.f) - mean * mean;
  float r = rsqrtf(var + 1e-5f);
  st_ln(&yr[t],       (v0 - mean) * r * g[t]       + b[t]);
  st_ln(&yr[t + 256], (v1 - mean) * r * g[t + 256] + b[t + 256]);
  st_ln(&yr[t + 512], (v2 - mean) * r * g[t + 512] + b[t + 512]);
}

// ---------------- patch extraction ----------------
__global__ __launch_bounds__(256) void im2col_k(const float* __restrict__ x,
    short* __restrict__ A)
{
  int i = blockIdx.x * 256 + threadIdx.x;
  int k = i & 255, row = i >> 8;
  int px = k & 15, py = k >> 4;
  int gx = row & 31, gy = (row >> 5) & 31, b = row >> 10;
  A[i] = f2bf(x[((long)(b * 512) + gy * 16 + py) * 512 + gx * 16 + px]);
}

// ---------------- t = concat(cls, tok) + pos ----------------
__global__ __launch_bounds__(256) void assemble_k(const short* __restrict__ tok,
    const float* __restrict__ cls, const float* __restrict__ pos, float* __restrict__ t)
{
  int i = blockIdx.x * 256 + threadIdx.x;
  int d = i % 768; int rn = i / 768; int n = rn % 1025; int b = rn / 1025;
  float v = (n == 0) ? cls[d] : bf2f(tok[((long)(b * 1024 + n - 1)) * 768 + d]);
  t[i] = v + pos[n * 768 + d];
}

extern "C" void kernel_launch(void* const* d_in, const int* in_sizes, int n_in,
                              void* d_out, int out_size, void* d_ws, size_t ws_size,
                              hipStream_t stream)
{
  const float* x       = (const float*)d_in[0];
  const float* conv_w  = (const float*)d_in[1];
  const float* conv_b  = (const float*)d_in[2];
  const float* cls     = (const float*)d_in[3];
  const float* pos     = (const float*)d_in[4];
  const float* qkv_w   = (const float*)d_in[5];
  const float* merge_w = (const float*)d_in[6];
  const float* merge_b = (const float*)d_in[7];
  const float* ln1_s   = (const float*)d_in[8];
  const float* ln1_b   = (const float*)d_in[9];
  const float* ln2_s   = (const float*)d_in[10];
  const float* ln2_b   = (const float*)d_in[11];
  const float* ffn_w1  = (const float*)d_in[12];
  const float* ffn_b1  = (const float*)d_in[13];
  const float* ffn_w2  = (const float*)d_in[14];
  const float* ffn_b2  = (const float*)d_in[15];
  const float* lnf_s   = (const float*)d_in[16];
  const float* lnf_b   = (const float*)d_in[17];

  char* wsp = (char*)d_ws;
  size_t o = 0;
  auto take = [&](size_t bytes) { char* r = wsp + o; o = (o + bytes + 255) & ~(size_t)255; return r; };
  short* wq   = (short*)take(1536ul * 768 * 2);
  short* wm   = (short*)take(768ul * 512 * 2);
  short* wf1  = (short*)take(2048ul * 768 * 2);
  short* wf2  = (short*)take(768ul * 2048 * 2);
  short* wcv  = (short*)take(768ul * 256 * 2);
  float* t    = (float*)take(4100ul * 768 * 4);
  char*  hO   = take(4352ul * 768 * 2);              // h bf16 OR O bf16 (rows padded)
  short* qkv  = (short*)take(4ul * 1025 * 1536 * 2);
  char*  fV   = take(4352ul * 2048 * 2);             // f (padded) OR (im2col + tok)
  take(2ul << 20);                                   // slack for tile over-reads

  short* h   = (short*)hO;
  short* O   = (short*)hO;
  short* f   = (short*)fV;
  short* imc = (short*)fV;
  short* tok = (short*)(fV + 4096ul * 256 * 2);

  dim3 blk(256);

  // ---- patch embed ----
  cvt_k<<<768, blk, 0, stream>>>(conv_w, wcv, 768 * 256);
  im2col_k<<<4096, blk, 0, stream>>>(x, imc);
  gemm_t<64><<<dim3(12, 64), blk, 0, stream>>>(imc, wcv, tok, conv_b,
      4096, 768, 256, 256, 256, 768, 1 | 8);
  assemble_k<<<12300, blk, 0, stream>>>(tok, cls, pos, t);

  for (int i = 0; i < 12; ++i) {
    tconv4_k<<<4608, blk, 0, stream>>>(
        qkv_w + (long)i * 768 * 1536, merge_w + (long)i * 512 * 768,
        ffn_w1 + (long)i * 768 * 2048, ffn_w2 + (long)i * 2048 * 768,
        wq, wm, wf1, wf2);

    // h = LN1(t)
    ln_k<short><<<4100, blk, 0, stream>>>(t, ln1_s + i * 768, ln1_b + i * 768, h, 4100);
    // qkv = h @ qkv_w
    gemm_t<128><<<dim3(12, 65), blk, 0, stream>>>(h, wq, qkv, nullptr,
        4100, 1536, 768, 768, 768, 1536, 8);
    // fused attention -> O
    flash_k<<<544, blk, 0, stream>>>(qkv, O);
    // t += O @ merge_w + merge_b
    gemm_t<64><<<dim3(12, 65), blk, 0, stream>>>(O, wm, t, merge_b + i * 768,
        4100, 768, 512, 512, 512, 768, 1 | 4);
    // h = LN2(t)
    ln_k<short><<<4100, blk, 0, stream>>>(t, ln2_s + i * 768, ln2_b + i * 768, h, 4100);
    // f = GELU(h @ ffn_w1 + b1)
    gemm_t<128><<<dim3(16, 65), blk, 0, stream>>>(h, wf1, f, ffn_b1 + i * 2048,
        4100, 2048, 768, 768, 768, 2048, 1 | 2 | 8);
    // t += f @ ffn_w2 + b2
    gemm_t<64><<<dim3(12, 65), blk, 0, stream>>>(f, wf2, t, ffn_b2 + i * 768,
        4100, 768, 2048, 2048, 2048, 768, 1 | 4);
  }
  ln_k<float><<<4100, blk, 0, stream>>>(t, lnf_s, lnf_b, (float*)d_out, 4100);
}

// Round 11
// 2095.951 us; speedup vs baseline: 1.1658x; 1.0179x over previous
//
#include <hip/hip_runtime.h>

#define DEV __device__ __forceinline__

typedef short s8v __attribute__((ext_vector_type(8)));
typedef float f4v __attribute__((ext_vector_type(4)));
typedef unsigned int u32x2 __attribute__((ext_vector_type(2)));

DEV short f2bf(float f) {
  unsigned u = __float_as_uint(f);
  u += 0x7FFFu + ((u >> 16) & 1u);
  return (short)(u >> 16);
}
DEV short f2bf_fast(float f) {           // round-to-nearest, no tie-to-even (P in [0,1])
  return (short)((__float_as_uint(f) + 0x8000u) >> 16);
}
DEV float bf2f(short s) { return __uint_as_float(((unsigned)(unsigned short)s) << 16); }

DEV void gld_lds16(const short* g, short* l) {
  __builtin_amdgcn_global_load_lds(
      (const __attribute__((address_space(1))) void*)g,
      (__attribute__((address_space(3))) void*)l, 16, 0, 0);
}

// LDS transpose read: 16 lanes/group, lane gets column (lane&15) of the 4x16
// bf16 subtile whose base the group addresses (addr_l = tile_base + (lane&15)*8B).
DEV u32x2 trr(unsigned lds_byte) {
  u32x2 r;
  asm volatile("ds_read_b64_tr_b16 %0, %1" : "=&v"(r) : "v"(lds_byte));
  return r;
}

// XCD-bijective swizzle (m204)
DEV int xcd_swz(int id, int nwg) {
  int q8 = nwg >> 3, r8 = nwg & 7, xcd = id & 7, off = id >> 3;
  return (xcd < r8) ? (xcd * (q8 + 1) + off) : (r8 * (q8 + 1) + (xcd - r8) * q8 + off);
}

// ================= 64xBN tile bf16 BT GEMM, dbuf + chunk-swizzle =================
// BN=128: waves 1x4 (64x32 each). BN=64: waves 2x2 (32x32).
// flags: 1=+bias[col], 2=exact GELU, 4=accumulate into fp32 C, 8=bf16 out
template<int BN>
__global__ __launch_bounds__(256) void gemm_t(
    const short* __restrict__ A, const short* __restrict__ B, void* __restrict__ Cv,
    const float* __restrict__ bias,
    int M, int N, int K, int lda, int ldb, int ldc, int flags)
{
  constexpr int BPASS = BN / 32;
  constexpr int MI = (BN == 128) ? 4 : 2;
  __shared__ __align__(16) short As[2][64 * 64];
  __shared__ __align__(16) short Bs[2][BN * 64];
  int nwg = gridDim.x * gridDim.y;
  int idl = blockIdx.y * gridDim.x + blockIdx.x;
  int swz = xcd_swz(idl, nwg);
  int bx = swz % gridDim.x, by = swz / gridDim.x;
  int m0 = by * 64, n0 = bx * BN;
  int tid = threadIdx.x, lane = tid & 63, w = tid >> 6;
  int lr = lane & 15, kg = lane >> 4;
  int wrb = (BN == 128) ? 0 : (w >> 1) * 32;
  int wcb = (BN == 128) ? w * 32 : (w & 1) * 32;
  f4v acc[MI][2] = {};
  int NT = K >> 6;

#define STAGE(bufi, k0)                                                   \
  {                                                                       \
    _Pragma("unroll")                                                     \
    for (int p = 0; p < 2; ++p) {                                         \
      int ch = p * 256 + w * 64 + lane;                                   \
      int row = ch >> 3, c = (ch & 7) ^ (row & 7);                        \
      gld_lds16(A + (long)(m0 + row) * lda + (k0) + c * 8,                \
                &As[bufi][(p * 256 + w * 64) * 8]);                       \
    }                                                                     \
    _Pragma("unroll")                                                     \
    for (int p = 0; p < BPASS; ++p) {                                     \
      int ch = p * 256 + w * 64 + lane;                                   \
      int row = ch >> 3, c = (ch & 7) ^ (row & 7);                        \
      gld_lds16(B + (long)(n0 + row) * ldb + (k0) + c * 8,                \
                &Bs[bufi][(p * 256 + w * 64) * 8]);                       \
    }                                                                     \
  }

  STAGE(0, 0)
  for (int t = 0; t < NT; ++t) {
    int buf = t & 1;
    if (t + 1 < NT) {
      STAGE(buf ^ 1, (t + 1) * 64)
      if constexpr (BN == 128)
        asm volatile("s_waitcnt vmcnt(6)" ::: "memory");   // retire tile-t loads only
      else
        asm volatile("s_waitcnt vmcnt(4)" ::: "memory");
    } else {
      asm volatile("s_waitcnt vmcnt(0)" ::: "memory");
    }
    __builtin_amdgcn_s_barrier();
    #pragma unroll
    for (int ks = 0; ks < 2; ++ks) {
      s8v av[MI], bv[2];
      #pragma unroll
      for (int mi = 0; mi < MI; ++mi) {
        int row = wrb + mi * 16 + lr;
        int sl = (ks * 4 + kg) ^ (row & 7);
        av[mi] = *(const s8v*)&As[buf][row * 64 + sl * 8];
      }
      #pragma unroll
      for (int ni = 0; ni < 2; ++ni) {
        int row = wcb + ni * 16 + lr;
        int sl = (ks * 4 + kg) ^ (row & 7);
        bv[ni] = *(const s8v*)&Bs[buf][row * 64 + sl * 8];
      }
      #pragma unroll
      for (int mi = 0; mi < MI; ++mi)
        #pragma unroll
        for (int ni = 0; ni < 2; ++ni)
          acc[mi][ni] = __builtin_amdgcn_mfma_f32_16x16x32_bf16(av[mi], bv[ni], acc[mi][ni], 0, 0, 0);
    }
    asm volatile("s_waitcnt lgkmcnt(0)" ::: "memory");
    __builtin_amdgcn_s_barrier();
  }
#undef STAGE

  float* Cf = (float*)Cv;
  short* Cb = (short*)Cv;
  #pragma unroll
  for (int mi = 0; mi < MI; ++mi)
    #pragma unroll
    for (int ni = 0; ni < 2; ++ni) {
      int col = n0 + wcb + ni * 16 + lr;
      float bvv = (flags & 1) ? bias[col] : 0.f;
      #pragma unroll
      for (int j = 0; j < 4; ++j) {
        int row = m0 + wrb + mi * 16 + kg * 4 + j;
        if (row >= M) continue;
        float v = acc[mi][ni][j] + bvv;
        if (flags & 2) v = 0.5f * v * (1.f + erff(v * 0.70710678118f));
        long ci = (long)row * ldc + col;
        if (flags & 8) Cb[ci] = f2bf(v);
        else { if (flags & 4) v += Cf[ci]; Cf[ci] = v; }
      }
    }
}

// ---------------- fused flash attention: swapped QK^T + tr_b16 V reads ----------------
// qkv: [4][1025][1536] bf16 (Q +0, K +64, V +128 per head zh*192)
// O:   [4][1025][512]  bf16
// Main loop: 16 full tiles (no masks). Key 1024 handled in closed-form epilogue.
// V LDS layout: subtiled [key/4][d/16][4][16] via pre-swizzled global source;
// PV B-frag = ds_read_b64_tr_b16 pairs (lane gets V[key][d=ni*16+lr]).
__global__ __launch_bounds__(256) void flash_k(
    const short* __restrict__ qkv, short* __restrict__ O)
{
  int swz = xcd_swz(blockIdx.x, 544);
  int z = swz / 17, qt = swz - z * 17;
  int zb = z >> 3, zh = z & 7;
  const short* base = qkv + (long)zb * 1025 * 1536 + zh * 192;
  const short* Qg = base;
  const short* Kg = base + 64;
  const short* Vg = base + 128;
  int q0 = qt * 64;
  int tid = threadIdx.x, lane = tid & 63, w = tid >> 6;
  int lr = lane & 15, kg = lane >> 4;

  __shared__ __align__(16) short Ks[2][64 * 64];
  __shared__ __align__(16) short Vs[2][64 * 64];   // subtiled [16][4][4][16]

  // Q direct to registers (over-reads land in ws slack)
  s8v aq[2];
  {
    long qrow = q0 + w * 16 + lr;
    aq[0] = *(const s8v*)(Qg + qrow * 1536 + kg * 8);
    aq[1] = *(const s8v*)(Qg + qrow * 1536 + 32 + kg * 8);
  }

  unsigned vsbase = (unsigned)(unsigned long long)
      (__attribute__((address_space(3))) void*)&Vs[0][0];
  unsigned vtr = (unsigned)(lr * 8 + kg * 1024);   // lane part of tr addr

#define STAGE_K(bufi, kv0)                                                 \
  {                                                                        \
    int s0 = w * 128;                                                      \
    _Pragma("unroll")                                                      \
    for (int i = 0; i < 2; ++i) {                                          \
      int s = s0 + i * 64 + lane;                                          \
      int row = s >> 3, c = (s & 7) ^ (row & 7);                           \
      gld_lds16(Kg + (long)((kv0) + row) * 1536 + c * 8,                   \
                &Ks[bufi][(s0 + i * 64) * 8]);                             \
    }                                                                      \
  }
  // V: LDS chunk ch holds global V[(st>>2)*4 + r][(st&3)*16 + hh*8], st=ch>>3
#define STAGE_V(bufi, kv0)                                                 \
  {                                                                        \
    int s0 = w * 128;                                                      \
    _Pragma("unroll")                                                      \
    for (int i = 0; i < 2; ++i) {                                          \
      int ch = s0 + i * 64 + lane;                                         \
      int st = ch >> 3, r = (ch & 7) >> 1, hh = ch & 1;                    \
      int key = (kv0) + (st >> 2) * 4 + r;                                 \
      int d = (st & 3) * 16 + hh * 8;                                      \
      gld_lds16(Vg + (long)key * 1536 + d,                                 \
                &Vs[bufi][(s0 + i * 64) * 8]);                             \
    }                                                                      \
  }

  f4v acc[4] = {};
  float m_run = -3.0e38f, l_run = 0.f;
  const float C2 = 0.18033688011112042f;   // 0.125 * log2(e)

  // prologue: tile 0
  STAGE_K(0, 0)
  STAGE_V(0, 0)
  asm volatile("s_waitcnt vmcnt(0)" ::: "memory");
  __builtin_amdgcn_s_barrier();

  for (int kt = 0; kt < 16; ++kt) {
    int cur = kt & 1;
    int kv0 = kt * 64;
    if (kt < 15) {
      STAGE_K(cur ^ 1, kv0 + 64)
      STAGE_V(cur ^ 1, kv0 + 64)
    }

    // S^T = K Q^T : A = K-frag, B = Q regs; lane (lr,kg) gets S[key][q=lr]
    f4v sa[4] = {};
    __builtin_amdgcn_s_setprio(1);
    #pragma unroll
    for (int ni = 0; ni < 4; ++ni) {
      int row = ni * 16 + lr;
      #pragma unroll
      for (int ks = 0; ks < 2; ++ks) {
        int c = (ks * 4 + kg) ^ (row & 7);
        s8v kf = *(const s8v*)&Ks[cur][row * 64 + c * 8];
        sa[ni] = __builtin_amdgcn_mfma_f32_16x16x32_bf16(kf, aq[ks], sa[ni], 0, 0, 0);
      }
    }
    __builtin_amdgcn_s_setprio(0);

    // per-lane online softmax over 16 keys (q = lr), exp2 domain
    float sv[4][4], pv[4][4];
    float tm = -3.0e38f;
    #pragma unroll
    for (int ni = 0; ni < 4; ++ni)
      #pragma unroll
      for (int jj = 0; jj < 4; ++jj) {
        float s = sa[ni][jj] * C2;
        sv[ni][jj] = s;
        tm = fmaxf(tm, s);
      }
    tm = fmaxf(tm, __shfl_xor(tm, 16));
    tm = fmaxf(tm, __shfl_xor(tm, 32));
    float m_new = fmaxf(m_run, tm);
    float scale = exp2f(m_run - m_new);
    m_run = m_new;
    float ts = 0.f;
    #pragma unroll
    for (int ni = 0; ni < 4; ++ni)
      #pragma unroll
      for (int jj = 0; jj < 4; ++jj) {
        float p = exp2f(sv[ni][jj] - m_new);
        pv[ni][jj] = p;
        ts += p;
      }
    ts += __shfl_xor(ts, 16);
    ts += __shfl_xor(ts, 32);
    l_run = l_run * scale + ts;

    // rescale acc (rows q = kg*4+jj)
    float scq[4];
    #pragma unroll
    for (int jj = 0; jj < 4; ++jj)
      scq[jj] = __shfl(scale, kg * 4 + jj + 16 * kg);
    #pragma unroll
    for (int ni = 0; ni < 4; ++ni)
      #pragma unroll
      for (int jj = 0; jj < 4; ++jj) acc[ni][jj] *= scq[jj];

    // P -> bf16 pairs, register redistribution to PV A-frag (8 shfl)
    unsigned pr[4][2];
    #pragma unroll
    for (int ni = 0; ni < 4; ++ni)
      #pragma unroll
      for (int h = 0; h < 2; ++h) {
        unsigned lo = (unsigned)(unsigned short)f2bf_fast(pv[ni][2 * h]);
        unsigned hi = (unsigned)(unsigned short)f2bf_fast(pv[ni][2 * h + 1]);
        pr[ni][h] = lo | (hi << 16);
      }
    union PU { s8v v; unsigned u[4]; };
    PU apu[2];
    #pragma unroll
    for (int ks = 0; ks < 2; ++ks)
      #pragma unroll
      for (int t = 0; t < 4; ++t) {
        unsigned src = (kg & 2) ? pr[2 * ks + 1][t & 1] : pr[2 * ks][t & 1];
        apu[ks].u[t] = __shfl(src, lr + 16 * (2 * (kg & 1) + (t >> 1)));
      }

    // V B-frags via hardware transpose reads (16 x b64)
    u32x2 tr[4][2][2];
    unsigned vb = vsbase + (unsigned)cur * 8192u + vtr;
    #pragma unroll
    for (int ni = 0; ni < 4; ++ni)
      #pragma unroll
      for (int ks = 0; ks < 2; ++ks) {
        tr[ni][ks][0] = trr(vb + ni * 128 + ks * 4096);
        tr[ni][ks][1] = trr(vb + ni * 128 + ks * 4096 + 512);
      }
    asm volatile("s_waitcnt lgkmcnt(0)" ::: "memory");
    __builtin_amdgcn_sched_barrier(0);

    // O += P V
    __builtin_amdgcn_s_setprio(1);
    #pragma unroll
    for (int ni = 0; ni < 4; ++ni) {
      #pragma unroll
      for (int ks = 0; ks < 2; ++ks) {
        union { s8v v; u32x2 u2[2]; } bb;
        bb.u2[0] = tr[ni][ks][0];
        bb.u2[1] = tr[ni][ks][1];
        acc[ni] = __builtin_amdgcn_mfma_f32_16x16x32_bf16(apu[ks].v, bb.v, acc[ni], 0, 0, 0);
      }
    }
    __builtin_amdgcn_s_setprio(0);
    asm volatile("s_waitcnt lgkmcnt(0)" ::: "memory");
    asm volatile("s_waitcnt vmcnt(0)" ::: "memory");   // next-tile K/V staged
    __builtin_amdgcn_s_barrier();
  }
#undef STAGE_K
#undef STAGE_V

  // ---- epilogue: key 1024 (closed form) ----
  {
    s8v k0 = *(const s8v*)(Kg + 1024L * 1536 + kg * 8);
    s8v k1 = *(const s8v*)(Kg + 1024L * 1536 + 32 + kg * 8);
    float s = 0.f;
    #pragma unroll
    for (int j = 0; j < 8; ++j)
      s += bf2f(aq[0][j]) * bf2f(k0[j]) + bf2f(aq[1][j]) * bf2f(k1[j]);
    s += __shfl_xor(s, 16);
    s += __shfl_xor(s, 32);
    float sC = s * C2;
    float m_new = fmaxf(m_run, sC);
    float sc = exp2f(m_run - m_new);
    float p = exp2f(sC - m_new);
    l_run = l_run * sc + p;
    float vrow[4];
    #pragma unroll
    for (int ni = 0; ni < 4; ++ni)
      vrow[ni] = bf2f(Vg[1024L * 1536 + ni * 16 + lr]);
    float scq[4], pq[4];
    #pragma unroll
    for (int jj = 0; jj < 4; ++jj) {
      scq[jj] = __shfl(sc, kg * 4 + jj + 16 * kg);
      pq[jj]  = __shfl(p,  kg * 4 + jj + 16 * kg);
    }
    #pragma unroll
    for (int ni = 0; ni < 4; ++ni)
      #pragma unroll
      for (int jj = 0; jj < 4; ++jj)
        acc[ni][jj] = acc[ni][jj] * scq[jj] + pq[jj] * vrow[ni];
  }

  // normalize + write
  float linv = 1.f / l_run;
  float invq[4];
  #pragma unroll
  for (int jj = 0; jj < 4; ++jj)
    invq[jj] = __shfl(linv, kg * 4 + jj + 16 * kg);
  #pragma unroll
  for (int ni = 0; ni < 4; ++ni)
    #pragma unroll
    for (int jj = 0; jj < 4; ++jj) {
      int row = q0 + w * 16 + kg * 4 + jj;
      if (row < 1025)
        O[((long)(zb * 1025 + row)) * 512 + zh * 64 + ni * 16 + lr] = f2bf(acc[ni][jj] * invq[jj]);
    }
}

// ---------------- fused per-layer weight transpose+convert ----------------
DEV void tconv_body(const float* w, short* wt, int K, int N, int bx, int by, int tid)
{
  __shared__ float tile[32][33];
  int n0 = bx * 32, k0 = by * 32;
  int tx = tid & 31, ty = tid >> 5;
  #pragma unroll
  for (int j = 0; j < 4; ++j)
    tile[ty + j * 8][tx] = w[(long)(k0 + ty + j * 8) * N + n0 + tx];
  __syncthreads();
  #pragma unroll
  for (int j = 0; j < 4; ++j)
    wt[(long)(n0 + ty + j * 8) * K + k0 + tx] = f2bf(tile[tx][ty + j * 8]);
}

__global__ __launch_bounds__(256) void tconv4_k(
    const float* __restrict__ sq, const float* __restrict__ sm,
    const float* __restrict__ sf1, const float* __restrict__ sf2,
    short* __restrict__ dq, short* __restrict__ dm,
    short* __restrict__ df1, short* __restrict__ df2)
{
  int id = blockIdx.x, tid = threadIdx.x;
  if (id < 1152)       tconv_body(sq,  dq,  768, 1536, id % 48,          id / 48,          tid);
  else if (id < 1536)  tconv_body(sm,  dm,  512, 768,  (id - 1152) % 24, (id - 1152) / 24, tid);
  else if (id < 3072)  tconv_body(sf1, df1, 768, 2048, (id - 1536) % 64, (id - 1536) / 64, tid);
  else                 tconv_body(sf2, df2, 2048, 768, (id - 3072) % 24, (id - 3072) / 24, tid);
}

// ---------------- elementwise fp32 -> bf16 ----------------
__global__ __launch_bounds__(256) void cvt_k(const float* __restrict__ in,
    short* __restrict__ out, int n)
{
  int i = blockIdx.x * 256 + threadIdx.x;
  if (i < n) out[i] = f2bf(in[i]);
}

// ---------------- LayerNorm D=768 ----------------
DEV void st_ln(float* p, float v) { *p = v; }
DEV void st_ln(short* p, float v) { *p = f2bf(v); }

template<typename OT>
__global__ __launch_bounds__(256) void ln_k(const float* __restrict__ x,
    const float* __restrict__ g, const float* __restrict__ b,
    OT* __restrict__ y, int rows)
{
  int row = blockIdx.x;
  if (row >= rows) return;
  const float* xr = x + (long)row * 768;
  OT* yr = y + (long)row * 768;
  int t = threadIdx.x;
  float v0 = xr[t], v1 = xr[t + 256], v2 = xr[t + 512];
  float s = v0 + v1 + v2, s2 = v0 * v0 + v1 * v1 + v2 * v2;
  #pragma unroll
  for (int o = 32; o > 0; o >>= 1) { s += __shfl_down(s, o); s2 += __shfl_down(s2, o); }
  __shared__ float as_[4], as2_[4];
  if ((t & 63) == 0) { as_[t >> 6] = s; as2_[t >> 6] = s2; }
  __syncthreads();
  s = as_[0] + as_[1] + as_[2] + as_[3];
  s2 = as2_[0] + as2_[1] + as2_[2] + as2_[3];
  float mean = s * (1.f / 768.f);
  float var = s2 * (1.f / 768.f) - mean * mean;
  float r = rsqrtf(var + 1e-5f);
  st_ln(&yr[t],       (v0 - mean) * r * g[t]       + b[t]);
  st_ln(&yr[t + 256], (v1 - mean) * r * g[t + 256] + b[t + 256]);
  st_ln(&yr[t + 512], (v2 - mean) * r * g[t + 512] + b[t + 512]);
}

// ---------------- patch extraction ----------------
__global__ __launch_bounds__(256) void im2col_k(const float* __restrict__ x,
    short* __restrict__ A)
{
  int i = blockIdx.x * 256 + threadIdx.x;
  int k = i & 255, row = i >> 8;
  int px = k & 15, py = k >> 4;
  int gx = row & 31, gy = (row >> 5) & 31, b = row >> 10;
  A[i] = f2bf(x[((long)(b * 512) + gy * 16 + py) * 512 + gx * 16 + px]);
}

// ---------------- t = concat(cls, tok) + pos ----------------
__global__ __launch_bounds__(256) void assemble_k(const short* __restrict__ tok,
    const float* __restrict__ cls, const float* __restrict__ pos, float* __restrict__ t)
{
  int i = blockIdx.x * 256 + threadIdx.x;
  int d = i % 768; int rn = i / 768; int n = rn % 1025; int b = rn / 1025;
  float v = (n == 0) ? cls[d] : bf2f(tok[((long)(b * 1024 + n - 1)) * 768 + d]);
  t[i] = v + pos[n * 768 + d];
}

extern "C" void kernel_launch(void* const* d_in, const int* in_sizes, int n_in,
                              void* d_out, int out_size, void* d_ws, size_t ws_size,
                              hipStream_t stream)
{
  const float* x       = (const float*)d_in[0];
  const float* conv_w  = (const float*)d_in[1];
  const float* conv_b  = (const float*)d_in[2];
  const float* cls     = (const float*)d_in[3];
  const float* pos     = (const float*)d_in[4];
  const float* qkv_w   = (const float*)d_in[5];
  const float* merge_w = (const float*)d_in[6];
  const float* merge_b = (const float*)d_in[7];
  const float* ln1_s   = (const float*)d_in[8];
  const float* ln1_b   = (const float*)d_in[9];
  const float* ln2_s   = (const float*)d_in[10];
  const float* ln2_b   = (const float*)d_in[11];
  const float* ffn_w1  = (const float*)d_in[12];
  const float* ffn_b1  = (const float*)d_in[13];
  const float* ffn_w2  = (const float*)d_in[14];
  const float* ffn_b2  = (const float*)d_in[15];
  const float* lnf_s   = (const float*)d_in[16];
  const float* lnf_b   = (const float*)d_in[17];

  char* wsp = (char*)d_ws;
  size_t o = 0;
  auto take = [&](size_t bytes) { char* r = wsp + o; o = (o + bytes + 255) & ~(size_t)255; return r; };
  short* wq   = (short*)take(1536ul * 768 * 2);
  short* wm   = (short*)take(768ul * 512 * 2);
  short* wf1  = (short*)take(2048ul * 768 * 2);
  short* wf2  = (short*)take(768ul * 2048 * 2);
  short* wcv  = (short*)take(768ul * 256 * 2);
  float* t    = (float*)take(4100ul * 768 * 4);
  char*  hO   = take(4352ul * 768 * 2);              // h bf16 OR O bf16 (rows padded)
  short* qkv  = (short*)take(4ul * 1025 * 1536 * 2);
  char*  fV   = take(4352ul * 2048 * 2);             // f (padded) OR (im2col + tok)
  take(2ul << 20);                                   // slack for tile over-reads

  short* h   = (short*)hO;
  short* O   = (short*)hO;
  short* f   = (short*)fV;
  short* imc = (short*)fV;
  short* tok = (short*)(fV + 4096ul * 256 * 2);

  dim3 blk(256);

  // ---- patch embed ----
  cvt_k<<<768, blk, 0, stream>>>(conv_w, wcv, 768 * 256);
  im2col_k<<<4096, blk, 0, stream>>>(x, imc);
  gemm_t<64><<<dim3(12, 64), blk, 0, stream>>>(imc, wcv, tok, conv_b,
      4096, 768, 256, 256, 256, 768, 1 | 8);
  assemble_k<<<12300, blk, 0, stream>>>(tok, cls, pos, t);

  for (int i = 0; i < 12; ++i) {
    tconv4_k<<<4608, blk, 0, stream>>>(
        qkv_w + (long)i * 768 * 1536, merge_w + (long)i * 512 * 768,
        ffn_w1 + (long)i * 768 * 2048, ffn_w2 + (long)i * 2048 * 768,
        wq, wm, wf1, wf2);

    // h = LN1(t)
    ln_k<short><<<4100, blk, 0, stream>>>(t, ln1_s + i * 768, ln1_b + i * 768, h, 4100);
    // qkv = h @ qkv_w
    gemm_t<128><<<dim3(12, 65), blk, 0, stream>>>(h, wq, qkv, nullptr,
        4100, 1536, 768, 768, 768, 1536, 8);
    // fused attention -> O
    flash_k<<<544, blk, 0, stream>>>(qkv, O);
    // t += O @ merge_w + merge_b
    gemm_t<64><<<dim3(12, 65), blk, 0, stream>>>(O, wm, t, merge_b + i * 768,
        4100, 768, 512, 512, 512, 768, 1 | 4);
    // h = LN2(t)
    ln_k<short><<<4100, blk, 0, stream>>>(t, ln2_s + i * 768, ln2_b + i * 768, h, 4100);
    // f = GELU(h @ ffn_w1 + b1)
    gemm_t<128><<<dim3(16, 65), blk, 0, stream>>>(h, wf1, f, ffn_b1 + i * 2048,
        4100, 2048, 768, 768, 768, 2048, 1 | 2 | 8);
    // t += f @ ffn_w2 + b2
    gemm_t<64><<<dim3(12, 65), blk, 0, stream>>>(f, wf2, t, ffn_b2 + i * 768,
        4100, 768, 2048, 2048, 2048, 768, 1 | 4);
  }
  ln_k<float><<<4100, blk, 0, stream>>>(t, lnf_s, lnf_b, (float*)d_out, 4100);
}

// Round 12
// 2033.631 us; speedup vs baseline: 1.2015x; 1.0306x over previous
//
#include <hip/hip_runtime.h>

#define DEV __device__ __forceinline__

typedef short s8v __attribute__((ext_vector_type(8)));
typedef float f4v __attribute__((ext_vector_type(4)));
typedef unsigned int u32x2 __attribute__((ext_vector_type(2)));

DEV short f2bf(float f) {
  unsigned u = __float_as_uint(f);
  u += 0x7FFFu + ((u >> 16) & 1u);
  return (short)(u >> 16);
}
DEV short f2bf_fast(float f) {           // round-half-up (positive finite)
  return (short)((__float_as_uint(f) + 0x8000u) >> 16);
}
DEV float bf2f(short s) { return __uint_as_float(((unsigned)(unsigned short)s) << 16); }

DEV void gld_lds16(const short* g, short* l) {
  __builtin_amdgcn_global_load_lds(
      (const __attribute__((address_space(1))) void*)g,
      (__attribute__((address_space(3))) void*)l, 16, 0, 0);
}

// LDS transpose read (4x16 bf16 subtile, lane gets column lane&15)
DEV u32x2 trr(unsigned lds_byte) {
  u32x2 r;
  asm volatile("ds_read_b64_tr_b16 %0, %1" : "=&v"(r) : "v"(lds_byte));
  return r;
}

// XCD-bijective swizzle (m204)
DEV int xcd_swz(int id, int nwg) {
  int q8 = nwg >> 3, r8 = nwg & 7, xcd = id & 7, off = id >> 3;
  return (xcd < r8) ? (xcd * (q8 + 1) + off) : (r8 * (q8 + 1) + (xcd - r8) * q8 + off);
}

// ================= 64xBN tile bf16 BT GEMM, dbuf + chunk-swizzle =================
// BN=128: waves 1x4 (64x32 each). BN=64: waves 2x2 (32x32).
// flags: 1=+bias[col], 2=exact GELU, 4=accumulate into fp32 C, 8=bf16 out
template<int BN>
__global__ __launch_bounds__(256) void gemm_t(
    const short* __restrict__ A, const short* __restrict__ B, void* __restrict__ Cv,
    const float* __restrict__ bias,
    int M, int N, int K, int lda, int ldb, int ldc, int flags)
{
  constexpr int BPASS = BN / 32;
  constexpr int MI = (BN == 128) ? 4 : 2;
  __shared__ __align__(16) short As[2][64 * 64];
  __shared__ __align__(16) short Bs[2][BN * 64];
  int nwg = gridDim.x * gridDim.y;
  int idl = blockIdx.y * gridDim.x + blockIdx.x;
  int swz = xcd_swz(idl, nwg);
  int bx = swz % gridDim.x, by = swz / gridDim.x;
  int m0 = by * 64, n0 = bx * BN;
  int tid = threadIdx.x, lane = tid & 63, w = tid >> 6;
  int lr = lane & 15, kg = lane >> 4;
  int wrb = (BN == 128) ? 0 : (w >> 1) * 32;
  int wcb = (BN == 128) ? w * 32 : (w & 1) * 32;
  f4v acc[MI][2] = {};
  int NT = K >> 6;

#define STAGE(bufi, k0)                                                   \
  {                                                                       \
    _Pragma("unroll")                                                     \
    for (int p = 0; p < 2; ++p) {                                         \
      int ch = p * 256 + w * 64 + lane;                                   \
      int row = ch >> 3, c = (ch & 7) ^ (row & 7);                        \
      gld_lds16(A + (long)(m0 + row) * lda + (k0) + c * 8,                \
                &As[bufi][(p * 256 + w * 64) * 8]);                       \
    }                                                                     \
    _Pragma("unroll")                                                     \
    for (int p = 0; p < BPASS; ++p) {                                     \
      int ch = p * 256 + w * 64 + lane;                                   \
      int row = ch >> 3, c = (ch & 7) ^ (row & 7);                        \
      gld_lds16(B + (long)(n0 + row) * ldb + (k0) + c * 8,                \
                &Bs[bufi][(p * 256 + w * 64) * 8]);                       \
    }                                                                     \
  }

  STAGE(0, 0)
  for (int t = 0; t < NT; ++t) {
    int buf = t & 1;
    if (t + 1 < NT) {
      STAGE(buf ^ 1, (t + 1) * 64)
      if constexpr (BN == 128)
        asm volatile("s_waitcnt vmcnt(6)" ::: "memory");
      else
        asm volatile("s_waitcnt vmcnt(4)" ::: "memory");
    } else {
      asm volatile("s_waitcnt vmcnt(0)" ::: "memory");
    }
    __builtin_amdgcn_s_barrier();
    #pragma unroll
    for (int ks = 0; ks < 2; ++ks) {
      s8v av[MI], bv[2];
      #pragma unroll
      for (int mi = 0; mi < MI; ++mi) {
        int row = wrb + mi * 16 + lr;
        int sl = (ks * 4 + kg) ^ (row & 7);
        av[mi] = *(const s8v*)&As[buf][row * 64 + sl * 8];
      }
      #pragma unroll
      for (int ni = 0; ni < 2; ++ni) {
        int row = wcb + ni * 16 + lr;
        int sl = (ks * 4 + kg) ^ (row & 7);
        bv[ni] = *(const s8v*)&Bs[buf][row * 64 + sl * 8];
      }
      #pragma unroll
      for (int mi = 0; mi < MI; ++mi)
        #pragma unroll
        for (int ni = 0; ni < 2; ++ni)
          acc[mi][ni] = __builtin_amdgcn_mfma_f32_16x16x32_bf16(av[mi], bv[ni], acc[mi][ni], 0, 0, 0);
    }
    asm volatile("s_waitcnt lgkmcnt(0)" ::: "memory");
    __builtin_amdgcn_s_barrier();
  }
#undef STAGE

  float* Cf = (float*)Cv;
  short* Cb = (short*)Cv;
  #pragma unroll
  for (int mi = 0; mi < MI; ++mi)
    #pragma unroll
    for (int ni = 0; ni < 2; ++ni) {
      int col = n0 + wcb + ni * 16 + lr;
      float bvv = (flags & 1) ? bias[col] : 0.f;
      #pragma unroll
      for (int j = 0; j < 4; ++j) {
        int row = m0 + wrb + mi * 16 + kg * 4 + j;
        if (row >= M) continue;
        float v = acc[mi][ni][j] + bvv;
        if (flags & 2) v = 0.5f * v * (1.f + erff(v * 0.70710678118f));
        long ci = (long)row * ldc + col;
        if (flags & 8) Cb[ci] = f2bf(v);
        else { if (flags & 4) v += Cf[ci]; Cf[ci] = v; }
      }
    }
}

// ---------------- fused flash attention: swapped QK^T + tr_b16 V, 2-way KV split ----------------
// grid 1088 = 2 halves * 32 z * 17 qtiles. Half h covers kt in [h*8, h*8+8);
// h=1 additionally handles key 1024 (closed form).
// Opart: [2][32][1025][64] fp32 unnormalized; ML: [2][32][1025][2] (m*C2, l)
__global__ __launch_bounds__(256) void flash_k(
    const short* __restrict__ qkv, float* __restrict__ Opart, float* __restrict__ ML)
{
  int swz = xcd_swz(blockIdx.x, 1088);
  int h = swz / 544, rem = swz - h * 544;
  int z = rem / 17, qt = rem - z * 17;
  int zb = z >> 3, zh = z & 7;
  const short* base = qkv + (long)zb * 1025 * 1536 + zh * 192;
  const short* Qg = base;
  const short* Kg = base + 64;
  const short* Vg = base + 128;
  int q0 = qt * 64;
  int kt0 = h * 8;
  int tid = threadIdx.x, lane = tid & 63, w = tid >> 6;
  int lr = lane & 15, kg = lane >> 4;

  __shared__ __align__(16) short Ks[2][64 * 64];
  __shared__ __align__(16) short Vs[2][64 * 64];   // subtiled [16][4][4][16]

  s8v aq[2];
  {
    long qrow = q0 + w * 16 + lr;
    aq[0] = *(const s8v*)(Qg + qrow * 1536 + kg * 8);
    aq[1] = *(const s8v*)(Qg + qrow * 1536 + 32 + kg * 8);
  }

  unsigned vsbase = (unsigned)(unsigned long long)
      (__attribute__((address_space(3))) void*)&Vs[0][0];
  unsigned vtr = (unsigned)(lr * 8 + kg * 1024);

#define STAGE_K(bufi, kv0)                                                 \
  {                                                                        \
    int s0 = w * 128;                                                      \
    _Pragma("unroll")                                                      \
    for (int i = 0; i < 2; ++i) {                                          \
      int s = s0 + i * 64 + lane;                                          \
      int row = s >> 3, c = (s & 7) ^ (row & 7);                           \
      gld_lds16(Kg + (long)((kv0) + row) * 1536 + c * 8,                   \
                &Ks[bufi][(s0 + i * 64) * 8]);                             \
    }                                                                      \
  }
#define STAGE_V(bufi, kv0)                                                 \
  {                                                                        \
    int s0 = w * 128;                                                      \
    _Pragma("unroll")                                                      \
    for (int i = 0; i < 2; ++i) {                                          \
      int ch = s0 + i * 64 + lane;                                         \
      int st = ch >> 3, r = (ch & 7) >> 1, hh = ch & 1;                    \
      int key = (kv0) + (st >> 2) * 4 + r;                                 \
      int d = (st & 3) * 16 + hh * 8;                                      \
      gld_lds16(Vg + (long)key * 1536 + d,                                 \
                &Vs[bufi][(s0 + i * 64) * 8]);                             \
    }                                                                      \
  }

  f4v acc[4] = {};
  float m_run = -3.0e38f, l_run = 0.f;
  const float C2 = 0.18033688011112042f;   // 0.125 * log2(e)
  const float THR = 44.36f;                // 8 exp2-units in raw-score units

  STAGE_K(0, kt0 * 64)
  STAGE_V(0, kt0 * 64)
  asm volatile("s_waitcnt vmcnt(0)" ::: "memory");
  __builtin_amdgcn_s_barrier();

  for (int kt = kt0; kt < kt0 + 8; ++kt) {
    int cur = (kt - kt0) & 1;
    if (kt + 1 < kt0 + 8) {
      STAGE_K(cur ^ 1, (kt + 1) * 64)
      STAGE_V(cur ^ 1, (kt + 1) * 64)
    }

    // S^T = K Q^T (raw scores in sa; lane (lr,kg): S[key][q=lr])
    f4v sa[4] = {};
    __builtin_amdgcn_s_setprio(1);
    #pragma unroll
    for (int ni = 0; ni < 4; ++ni) {
      int row = ni * 16 + lr;
      #pragma unroll
      for (int ks = 0; ks < 2; ++ks) {
        int c = (ks * 4 + kg) ^ (row & 7);
        s8v kf = *(const s8v*)&Ks[cur][row * 64 + c * 8];
        sa[ni] = __builtin_amdgcn_mfma_f32_16x16x32_bf16(kf, aq[ks], sa[ni], 0, 0, 0);
      }
    }
    __builtin_amdgcn_s_setprio(0);

    // per-lane online softmax (raw-unit max tracking, defer-max)
    float tm = -3.0e38f;
    #pragma unroll
    for (int ni = 0; ni < 4; ++ni)
      #pragma unroll
      for (int jj = 0; jj < 4; ++jj) tm = fmaxf(tm, sa[ni][jj]);
    tm = fmaxf(tm, __shfl_xor(tm, 16));
    tm = fmaxf(tm, __shfl_xor(tm, 32));
    bool need = !__all(tm <= m_run + THR);
    float scale = 1.f;
    if (need) {
      float m_new = fmaxf(m_run, tm);
      scale = exp2f((m_run - m_new) * C2);
      m_run = m_new;
    }
    float mC = m_run * C2;
    float pv[4][4];
    float ts = 0.f;
    #pragma unroll
    for (int ni = 0; ni < 4; ++ni)
      #pragma unroll
      for (int jj = 0; jj < 4; ++jj) {
        float p = exp2f(fmaf(sa[ni][jj], C2, -mC));
        pv[ni][jj] = p;
        ts += p;
      }
    ts += __shfl_xor(ts, 16);
    ts += __shfl_xor(ts, 32);
    l_run = l_run * scale + ts;
    if (need) {
      float scq[4];
      #pragma unroll
      for (int jj = 0; jj < 4; ++jj)
        scq[jj] = __shfl(scale, kg * 4 + jj + 16 * kg);
      #pragma unroll
      for (int ni = 0; ni < 4; ++ni)
        #pragma unroll
        for (int jj = 0; jj < 4; ++jj) acc[ni][jj] *= scq[jj];
    }

    // P -> bf16 pairs, register redistribution to PV A-frag (8 shfl)
    unsigned pr[4][2];
    #pragma unroll
    for (int ni = 0; ni < 4; ++ni)
      #pragma unroll
      for (int hh = 0; hh < 2; ++hh) {
        unsigned lo = (unsigned)(unsigned short)f2bf_fast(pv[ni][2 * hh]);
        unsigned hi = (unsigned)(unsigned short)f2bf_fast(pv[ni][2 * hh + 1]);
        pr[ni][hh] = lo | (hi << 16);
      }
    union PU { s8v v; unsigned u[4]; };
    PU apu[2];
    #pragma unroll
    for (int ks = 0; ks < 2; ++ks)
      #pragma unroll
      for (int t = 0; t < 4; ++t) {
        unsigned src = (kg & 2) ? pr[2 * ks + 1][t & 1] : pr[2 * ks][t & 1];
        apu[ks].u[t] = __shfl(src, lr + 16 * (2 * (kg & 1) + (t >> 1)));
      }

    // V B-frags via hardware transpose reads
    u32x2 tr[4][2][2];
    unsigned vb = vsbase + (unsigned)cur * 8192u + vtr;
    #pragma unroll
    for (int ni = 0; ni < 4; ++ni)
      #pragma unroll
      for (int ks = 0; ks < 2; ++ks) {
        tr[ni][ks][0] = trr(vb + ni * 128 + ks * 4096);
        tr[ni][ks][1] = trr(vb + ni * 128 + ks * 4096 + 512);
      }
    asm volatile("s_waitcnt lgkmcnt(0)" ::: "memory");
    __builtin_amdgcn_sched_barrier(0);

    // O += P V
    __builtin_amdgcn_s_setprio(1);
    #pragma unroll
    for (int ni = 0; ni < 4; ++ni) {
      #pragma unroll
      for (int ks = 0; ks < 2; ++ks) {
        union { s8v v; u32x2 u2[2]; } bb;
        bb.u2[0] = tr[ni][ks][0];
        bb.u2[1] = tr[ni][ks][1];
        acc[ni] = __builtin_amdgcn_mfma_f32_16x16x32_bf16(apu[ks].v, bb.v, acc[ni], 0, 0, 0);
      }
    }
    __builtin_amdgcn_s_setprio(0);
    asm volatile("s_waitcnt lgkmcnt(0)" ::: "memory");
    asm volatile("s_waitcnt vmcnt(0)" ::: "memory");
    __builtin_amdgcn_s_barrier();
  }
#undef STAGE_K
#undef STAGE_V

  // ---- h=1: key 1024 closed form ----
  if (h) {
    s8v k0 = *(const s8v*)(Kg + 1024L * 1536 + kg * 8);
    s8v k1 = *(const s8v*)(Kg + 1024L * 1536 + 32 + kg * 8);
    float s = 0.f;
    #pragma unroll
    for (int j = 0; j < 8; ++j)
      s += bf2f(aq[0][j]) * bf2f(k0[j]) + bf2f(aq[1][j]) * bf2f(k1[j]);
    s += __shfl_xor(s, 16);
    s += __shfl_xor(s, 32);
    float m_new = fmaxf(m_run, s);
    float sc = exp2f((m_run - m_new) * C2);
    float p = exp2f((s - m_new) * C2);
    m_run = m_new;
    l_run = l_run * sc + p;
    float vrow[4];
    #pragma unroll
    for (int ni = 0; ni < 4; ++ni)
      vrow[ni] = bf2f(Vg[1024L * 1536 + ni * 16 + lr]);
    float scq[4], pq[4];
    #pragma unroll
    for (int jj = 0; jj < 4; ++jj) {
      scq[jj] = __shfl(sc, kg * 4 + jj + 16 * kg);
      pq[jj]  = __shfl(p,  kg * 4 + jj + 16 * kg);
    }
    #pragma unroll
    for (int ni = 0; ni < 4; ++ni)
      #pragma unroll
      for (int jj = 0; jj < 4; ++jj)
        acc[ni][jj] = acc[ni][jj] * scq[jj] + pq[jj] * vrow[ni];
  }

  // ---- write unnormalized partial + (m*C2, l) ----
  long zrow = (long)(h * 32 + z) * 1025;
  if (kg == 0) {
    int row = q0 + w * 16 + lr;
    if (row < 1025) {
      ML[(zrow + row) * 2]     = m_run * C2;
      ML[(zrow + row) * 2 + 1] = l_run;
    }
  }
  #pragma unroll
  for (int ni = 0; ni < 4; ++ni)
    #pragma unroll
    for (int jj = 0; jj < 4; ++jj) {
      int row = q0 + w * 16 + kg * 4 + jj;
      if (row < 1025)
        Opart[(zrow + row) * 64 + ni * 16 + lr] = acc[ni][jj];
    }
}

// ---------------- combine halves -> O bf16 [4][1025][512] ----------------
__global__ __launch_bounds__(256) void fcomb_k(
    const float* __restrict__ Opart, const float* __restrict__ ML, short* __restrict__ O)
{
  int idx = blockIdx.x * 256 + threadIdx.x;   // 32*1025*64
  int d = idx & 63;
  int r = idx >> 6;                            // z*1025 + row
  int z = r / 1025, row = r - z * 1025;
  float m0 = ML[(long)r * 2], l0 = ML[(long)r * 2 + 1];
  float m1 = ML[(long)(32800 + r) * 2], l1 = ML[(long)(32800 + r) * 2 + 1];
  float M = fmaxf(m0, m1);
  float w0 = exp2f(m0 - M), w1 = exp2f(m1 - M);
  float inv = 1.f / (l0 * w0 + l1 * w1);
  float v = (Opart[(long)r * 64 + d] * w0 + Opart[(long)(32800 + r) * 64 + d] * w1) * inv;
  int zb = z >> 3, zh = z & 7;
  O[((long)(zb * 1025 + row)) * 512 + zh * 64 + d] = f2bf(v);
}

// ---------------- fused per-layer weight transpose+convert ----------------
DEV void tconv_body(const float* w, short* wt, int K, int N, int bx, int by, int tid)
{
  __shared__ float tile[32][33];
  int n0 = bx * 32, k0 = by * 32;
  int tx = tid & 31, ty = tid >> 5;
  #pragma unroll
  for (int j = 0; j < 4; ++j)
    tile[ty + j * 8][tx] = w[(long)(k0 + ty + j * 8) * N + n0 + tx];
  __syncthreads();
  #pragma unroll
  for (int j = 0; j < 4; ++j)
    wt[(long)(n0 + ty + j * 8) * K + k0 + tx] = f2bf(tile[tx][ty + j * 8]);
}

__global__ __launch_bounds__(256) void tconv4_k(
    const float* __restrict__ sq, const float* __restrict__ sm,
    const float* __restrict__ sf1, const float* __restrict__ sf2,
    short* __restrict__ dq, short* __restrict__ dm,
    short* __restrict__ df1, short* __restrict__ df2)
{
  int id = blockIdx.x, tid = threadIdx.x;
  if (id < 1152)       tconv_body(sq,  dq,  768, 1536, id % 48,          id / 48,          tid);
  else if (id < 1536)  tconv_body(sm,  dm,  512, 768,  (id - 1152) % 24, (id - 1152) / 24, tid);
  else if (id < 3072)  tconv_body(sf1, df1, 768, 2048, (id - 1536) % 64, (id - 1536) / 64, tid);
  else                 tconv_body(sf2, df2, 2048, 768, (id - 3072) % 24, (id - 3072) / 24, tid);
}

// ---------------- elementwise fp32 -> bf16 ----------------
__global__ __launch_bounds__(256) void cvt_k(const float* __restrict__ in,
    short* __restrict__ out, int n)
{
  int i = blockIdx.x * 256 + threadIdx.x;
  if (i < n) out[i] = f2bf(in[i]);
}

// ---------------- LayerNorm D=768 ----------------
DEV void st_ln(float* p, float v) { *p = v; }
DEV void st_ln(short* p, float v) { *p = f2bf(v); }

template<typename OT>
__global__ __launch_bounds__(256) void ln_k(const float* __restrict__ x,
    const float* __restrict__ g, const float* __restrict__ b,
    OT* __restrict__ y, int rows)
{
  int row = blockIdx.x;
  if (row >= rows) return;
  const float* xr = x + (long)row * 768;
  OT* yr = y + (long)row * 768;
  int t = threadIdx.x;
  float v0 = xr[t], v1 = xr[t + 256], v2 = xr[t + 512];
  float s = v0 + v1 + v2, s2 = v0 * v0 + v1 * v1 + v2 * v2;
  #pragma unroll
  for (int o = 32; o > 0; o >>= 1) { s += __shfl_down(s, o); s2 += __shfl_down(s2, o); }
  __shared__ float as_[4], as2_[4];
  if ((t & 63) == 0) { as_[t >> 6] = s; as2_[t >> 6] = s2; }
  __syncthreads();
  s = as_[0] + as_[1] + as_[2] + as_[3];
  s2 = as2_[0] + as2_[1] + as2_[2] + as2_[3];
  float mean = s * (1.f / 768.f);
  float var = s2 * (1.f / 768.f) - mean * mean;
  float r = rsqrtf(var + 1e-5f);
  st_ln(&yr[t],       (v0 - mean) * r * g[t]       + b[t]);
  st_ln(&yr[t + 256], (v1 - mean) * r * g[t + 256] + b[t + 256]);
  st_ln(&yr[t + 512], (v2 - mean) * r * g[t + 512] + b[t + 512]);
}

// ---------------- patch extraction ----------------
__global__ __launch_bounds__(256) void im2col_k(const float* __restrict__ x,
    short* __restrict__ A)
{
  int i = blockIdx.x * 256 + threadIdx.x;
  int k = i & 255, row = i >> 8;
  int px = k & 15, py = k >> 4;
  int gx = row & 31, gy = (row >> 5) & 31, b = row >> 10;
  A[i] = f2bf(x[((long)(b * 512) + gy * 16 + py) * 512 + gx * 16 + px]);
}

// ---------------- t = concat(cls, tok) + pos ----------------
__global__ __launch_bounds__(256) void assemble_k(const short* __restrict__ tok,
    const float* __restrict__ cls, const float* __restrict__ pos, float* __restrict__ t)
{
  int i = blockIdx.x * 256 + threadIdx.x;
  int d = i % 768; int rn = i / 768; int n = rn % 1025; int b = rn / 1025;
  float v = (n == 0) ? cls[d] : bf2f(tok[((long)(b * 1024 + n - 1)) * 768 + d]);
  t[i] = v + pos[n * 768 + d];
}

extern "C" void kernel_launch(void* const* d_in, const int* in_sizes, int n_in,
                              void* d_out, int out_size, void* d_ws, size_t ws_size,
                              hipStream_t stream)
{
  const float* x       = (const float*)d_in[0];
  const float* conv_w  = (const float*)d_in[1];
  const float* conv_b  = (const float*)d_in[2];
  const float* cls     = (const float*)d_in[3];
  const float* pos     = (const float*)d_in[4];
  const float* qkv_w   = (const float*)d_in[5];
  const float* merge_w = (const float*)d_in[6];
  const float* merge_b = (const float*)d_in[7];
  const float* ln1_s   = (const float*)d_in[8];
  const float* ln1_b   = (const float*)d_in[9];
  const float* ln2_s   = (const float*)d_in[10];
  const float* ln2_b   = (const float*)d_in[11];
  const float* ffn_w1  = (const float*)d_in[12];
  const float* ffn_b1  = (const float*)d_in[13];
  const float* ffn_w2  = (const float*)d_in[14];
  const float* ffn_b2  = (const float*)d_in[15];
  const float* lnf_s   = (const float*)d_in[16];
  const float* lnf_b   = (const float*)d_in[17];

  char* wsp = (char*)d_ws;
  size_t o = 0;
  auto take = [&](size_t bytes) { char* r = wsp + o; o = (o + bytes + 255) & ~(size_t)255; return r; };
  short* wq   = (short*)take(1536ul * 768 * 2);
  short* wm   = (short*)take(768ul * 512 * 2);
  short* wf1  = (short*)take(2048ul * 768 * 2);
  short* wf2  = (short*)take(768ul * 2048 * 2);
  short* wcv  = (short*)take(768ul * 256 * 2);
  float* t    = (float*)take(4100ul * 768 * 4);
  char*  hO   = take(4352ul * 768 * 2);              // h bf16 OR O bf16 (rows padded)
  short* qkv  = (short*)take(4ul * 1025 * 1536 * 2);
  char*  fV   = take(4352ul * 2048 * 2);             // f (padded) OR (im2col+tok) OR (Opart+ML)
  take(2ul << 20);                                   // slack for tile over-reads

  short* h     = (short*)hO;
  short* O     = (short*)hO;
  short* f     = (short*)fV;
  short* imc   = (short*)fV;
  short* tok   = (short*)(fV + 4096ul * 256 * 2);
  float* Opart = (float*)fV;                          // 16,793,600 B
  float* ML    = (float*)(fV + 16793600);             // 524,800 B

  dim3 blk(256);

  // ---- patch embed ----
  cvt_k<<<768, blk, 0, stream>>>(conv_w, wcv, 768 * 256);
  im2col_k<<<4096, blk, 0, stream>>>(x, imc);
  gemm_t<64><<<dim3(12, 64), blk, 0, stream>>>(imc, wcv, tok, conv_b,
      4096, 768, 256, 256, 256, 768, 1 | 8);
  assemble_k<<<12300, blk, 0, stream>>>(tok, cls, pos, t);

  for (int i = 0; i < 12; ++i) {
    tconv4_k<<<4608, blk, 0, stream>>>(
        qkv_w + (long)i * 768 * 1536, merge_w + (long)i * 512 * 768,
        ffn_w1 + (long)i * 768 * 2048, ffn_w2 + (long)i * 2048 * 768,
        wq, wm, wf1, wf2);

    // h = LN1(t)
    ln_k<short><<<4100, blk, 0, stream>>>(t, ln1_s + i * 768, ln1_b + i * 768, h, 4100);
    // qkv = h @ qkv_w
    gemm_t<64><<<dim3(24, 65), blk, 0, stream>>>(h, wq, qkv, nullptr,
        4100, 1536, 768, 768, 768, 1536, 8);
    // fused attention (2-way KV split) -> partials -> O
    flash_k<<<1088, blk, 0, stream>>>(qkv, Opart, ML);
    fcomb_k<<<8200, blk, 0, stream>>>(Opart, ML, O);
    // t += O @ merge_w + merge_b
    gemm_t<64><<<dim3(12, 65), blk, 0, stream>>>(O, wm, t, merge_b + i * 768,
        4100, 768, 512, 512, 512, 768, 1 | 4);
    // h = LN2(t)
    ln_k<short><<<4100, blk, 0, stream>>>(t, ln2_s + i * 768, ln2_b + i * 768, h, 4100);
    // f = GELU(h @ ffn_w1 + b1)
    gemm_t<64><<<dim3(32, 65), blk, 0, stream>>>(h, wf1, f, ffn_b1 + i * 2048,
        4100, 2048, 768, 768, 768, 2048, 1 | 2 | 8);
    // t += f @ ffn_w2 + b2
    gemm_t<64><<<dim3(12, 65), blk, 0, stream>>>(f, wf2, t, ffn_b2 + i * 768,
        4100, 768, 2048, 2048, 2048, 768, 1 | 4);
  }
  ln_k<float><<<4100, blk, 0, stream>>>(t, lnf_s, lnf_b, (float*)d_out, 4100);
}

// Round 13
// 1969.169 us; speedup vs baseline: 1.2408x; 1.0327x over previous
//
#include <hip/hip_runtime.h>

#define DEV __device__ __forceinline__

typedef short s4v __attribute__((ext_vector_type(4)));
typedef short s8v __attribute__((ext_vector_type(8)));
typedef float f4v __attribute__((ext_vector_type(4)));
typedef unsigned int u32x2 __attribute__((ext_vector_type(2)));

DEV short f2bf(float f) {
  unsigned u = __float_as_uint(f);
  u += 0x7FFFu + ((u >> 16) & 1u);
  return (short)(u >> 16);
}
DEV short f2bf_fast(float f) {           // round-half-up (positive finite)
  return (short)((__float_as_uint(f) + 0x8000u) >> 16);
}
DEV float bf2f(short s) { return __uint_as_float(((unsigned)(unsigned short)s) << 16); }

DEV void gld_lds16(const short* g, short* l) {
  __builtin_amdgcn_global_load_lds(
      (const __attribute__((address_space(1))) void*)g,
      (__attribute__((address_space(3))) void*)l, 16, 0, 0);
}

// LDS transpose read (4x16 bf16 subtile, lane gets column lane&15)
DEV u32x2 trr(unsigned lds_byte) {
  u32x2 r;
  asm volatile("ds_read_b64_tr_b16 %0, %1" : "=&v"(r) : "v"(lds_byte));
  return r;
}

// XCD-bijective swizzle (m204)
DEV int xcd_swz(int id, int nwg) {
  int q8 = nwg >> 3, r8 = nwg & 7, xcd = id & 7, off = id >> 3;
  return (xcd < r8) ? (xcd * (q8 + 1) + off) : (r8 * (q8 + 1) + (xcd - r8) * q8 + off);
}

// ================= 64xBN tile bf16 BT GEMM, dbuf + chunk-swizzle =================
// BN=128: waves 1x4 (64x32 each). BN=64: waves 2x2 (32x32).
// flags: 1=+bias[col], 2=exact GELU, 4=accumulate into fp32 C, 8=bf16 out
template<int BN>
__global__ __launch_bounds__(256) void gemm_t(
    const short* __restrict__ A, const short* __restrict__ B, void* __restrict__ Cv,
    const float* __restrict__ bias,
    int M, int N, int K, int lda, int ldb, int ldc, int flags)
{
  constexpr int BPASS = BN / 32;
  constexpr int MI = (BN == 128) ? 4 : 2;
  __shared__ __align__(16) short As[2][64 * 64];
  __shared__ __align__(16) short Bs[2][BN * 64];
  int nwg = gridDim.x * gridDim.y;
  int idl = blockIdx.y * gridDim.x + blockIdx.x;
  int swz = xcd_swz(idl, nwg);
  int bx = swz % gridDim.x, by = swz / gridDim.x;
  int m0 = by * 64, n0 = bx * BN;
  int tid = threadIdx.x, lane = tid & 63, w = tid >> 6;
  int lr = lane & 15, kg = lane >> 4;
  int wrb = (BN == 128) ? 0 : (w >> 1) * 32;
  int wcb = (BN == 128) ? w * 32 : (w & 1) * 32;
  f4v acc[MI][2] = {};
  int NT = K >> 6;

#define STAGE(bufi, k0)                                                   \
  {                                                                       \
    _Pragma("unroll")                                                     \
    for (int p = 0; p < 2; ++p) {                                         \
      int ch = p * 256 + w * 64 + lane;                                   \
      int row = ch >> 3, c = (ch & 7) ^ (row & 7);                        \
      gld_lds16(A + (long)(m0 + row) * lda + (k0) + c * 8,                \
                &As[bufi][(p * 256 + w * 64) * 8]);                       \
    }                                                                     \
    _Pragma("unroll")                                                     \
    for (int p = 0; p < BPASS; ++p) {                                     \
      int ch = p * 256 + w * 64 + lane;                                   \
      int row = ch >> 3, c = (ch & 7) ^ (row & 7);                        \
      gld_lds16(B + (long)(n0 + row) * ldb + (k0) + c * 8,                \
                &Bs[bufi][(p * 256 + w * 64) * 8]);                       \
    }                                                                     \
  }

  STAGE(0, 0)
  for (int t = 0; t < NT; ++t) {
    int buf = t & 1;
    if (t + 1 < NT) {
      STAGE(buf ^ 1, (t + 1) * 64)
      if constexpr (BN == 128)
        asm volatile("s_waitcnt vmcnt(6)" ::: "memory");
      else
        asm volatile("s_waitcnt vmcnt(4)" ::: "memory");
    } else {
      asm volatile("s_waitcnt vmcnt(0)" ::: "memory");
    }
    __builtin_amdgcn_s_barrier();
    #pragma unroll
    for (int ks = 0; ks < 2; ++ks) {
      s8v av[MI], bv[2];
      #pragma unroll
      for (int mi = 0; mi < MI; ++mi) {
        int row = wrb + mi * 16 + lr;
        int sl = (ks * 4 + kg) ^ (row & 7);
        av[mi] = *(const s8v*)&As[buf][row * 64 + sl * 8];
      }
      #pragma unroll
      for (int ni = 0; ni < 2; ++ni) {
        int row = wcb + ni * 16 + lr;
        int sl = (ks * 4 + kg) ^ (row & 7);
        bv[ni] = *(const s8v*)&Bs[buf][row * 64 + sl * 8];
      }
      #pragma unroll
      for (int mi = 0; mi < MI; ++mi)
        #pragma unroll
        for (int ni = 0; ni < 2; ++ni)
          acc[mi][ni] = __builtin_amdgcn_mfma_f32_16x16x32_bf16(av[mi], bv[ni], acc[mi][ni], 0, 0, 0);
    }
    asm volatile("s_waitcnt lgkmcnt(0)" ::: "memory");
    __builtin_amdgcn_s_barrier();
  }
#undef STAGE

  float* Cf = (float*)Cv;
  short* Cb = (short*)Cv;
  #pragma unroll
  for (int mi = 0; mi < MI; ++mi)
    #pragma unroll
    for (int ni = 0; ni < 2; ++ni) {
      int col = n0 + wcb + ni * 16 + lr;
      float bvv = (flags & 1) ? bias[col] : 0.f;
      #pragma unroll
      for (int j = 0; j < 4; ++j) {
        int row = m0 + wrb + mi * 16 + kg * 4 + j;
        if (row >= M) continue;
        float v = acc[mi][ni][j] + bvv;
        if (flags & 2) v = 0.5f * v * (1.f + erff(v * 0.70710678118f));
        long ci = (long)row * ldc + col;
        if (flags & 8) Cb[ci] = f2bf(v);
        else { if (flags & 4) v += Cf[ci]; Cf[ci] = v; }
      }
    }
}

// ---------------- fused flash attention: in-block 2-way KV split ----------------
// grid 544 = 32 z * 17 qtiles; block 512 = 2 groups * 4 waves.
// Group g handles K-tiles [8g, 8g+8); g=1 also key 1024. Combine via LDS.
__global__ __launch_bounds__(512) void flash_k(
    const short* __restrict__ qkv, short* __restrict__ O)
{
  int swz = xcd_swz(blockIdx.x, 544);
  int z = swz / 17, qt = swz - z * 17;
  int zb = z >> 3, zh = z & 7;
  const short* base = qkv + (long)zb * 1025 * 1536 + zh * 192;
  const short* Qg = base;
  const short* Kg = base + 64;
  const short* Vg = base + 128;
  int q0 = qt * 64;
  int tid = threadIdx.x, lane = tid & 63, w = tid >> 6;   // w in 0..7
  int g = w >> 2, wl = w & 3;
  int lr = lane & 15, kg = lane >> 4;
  int kt0 = g * 8;

  __shared__ __align__(16) short Ks[2][2][64 * 64];   // [group][buf], 32 KB
  __shared__ __align__(16) short Vs[2][2][64 * 64];   // subtiled, 32 KB

  s8v aq[2];
  {
    long qrow = q0 + wl * 16 + lr;
    aq[0] = *(const s8v*)(Qg + qrow * 1536 + kg * 8);
    aq[1] = *(const s8v*)(Qg + qrow * 1536 + 32 + kg * 8);
  }

  unsigned vsbase = (unsigned)(unsigned long long)
      (__attribute__((address_space(3))) void*)&Vs[0][0][0];
  unsigned vtr = (unsigned)(lr * 8 + kg * 1024);

#define STAGE_K(bufi, kv0)                                                 \
  {                                                                        \
    int s0 = wl * 128;                                                     \
    _Pragma("unroll")                                                      \
    for (int i = 0; i < 2; ++i) {                                          \
      int s = s0 + i * 64 + lane;                                          \
      int row = s >> 3, c = (s & 7) ^ (row & 7);                           \
      gld_lds16(Kg + (long)((kv0) + row) * 1536 + c * 8,                   \
                &Ks[g][bufi][(s0 + i * 64) * 8]);                          \
    }                                                                      \
  }
#define STAGE_V(bufi, kv0)                                                 \
  {                                                                        \
    int s0 = wl * 128;                                                     \
    _Pragma("unroll")                                                      \
    for (int i = 0; i < 2; ++i) {                                          \
      int ch = s0 + i * 64 + lane;                                         \
      int st = ch >> 3, r = (ch & 7) >> 1, hh = ch & 1;                    \
      int key = (kv0) + (st >> 2) * 4 + r;                                 \
      int d = (st & 3) * 16 + hh * 8;                                      \
      gld_lds16(Vg + (long)key * 1536 + d,                                 \
                &Vs[g][bufi][(s0 + i * 64) * 8]);                          \
    }                                                                      \
  }

  f4v acc[4] = {};
  float m_run = -3.0e38f, l_run = 0.f;
  const float C2 = 0.18033688011112042f;   // 0.125 * log2(e)
  const float THR = 44.36f;                // 8 exp2-units in raw-score units

  STAGE_K(0, kt0 * 64)
  STAGE_V(0, kt0 * 64)
  asm volatile("s_waitcnt vmcnt(0)" ::: "memory");
  __builtin_amdgcn_s_barrier();

  for (int kt = kt0; kt < kt0 + 8; ++kt) {
    int cur = (kt - kt0) & 1;
    if (kt + 1 < kt0 + 8) {
      STAGE_K(cur ^ 1, (kt + 1) * 64)
      STAGE_V(cur ^ 1, (kt + 1) * 64)
    }

    // S^T = K Q^T (lane (lr,kg): S[key][q=lr], raw scores)
    f4v sa[4] = {};
    __builtin_amdgcn_s_setprio(1);
    #pragma unroll
    for (int ni = 0; ni < 4; ++ni) {
      int row = ni * 16 + lr;
      #pragma unroll
      for (int ks = 0; ks < 2; ++ks) {
        int c = (ks * 4 + kg) ^ (row & 7);
        s8v kf = *(const s8v*)&Ks[g][cur][row * 64 + c * 8];
        sa[ni] = __builtin_amdgcn_mfma_f32_16x16x32_bf16(kf, aq[ks], sa[ni], 0, 0, 0);
      }
    }
    __builtin_amdgcn_s_setprio(0);

    // per-lane online softmax (raw-unit max, defer-max)
    float tm = -3.0e38f;
    #pragma unroll
    for (int ni = 0; ni < 4; ++ni)
      #pragma unroll
      for (int jj = 0; jj < 4; ++jj) tm = fmaxf(tm, sa[ni][jj]);
    tm = fmaxf(tm, __shfl_xor(tm, 16));
    tm = fmaxf(tm, __shfl_xor(tm, 32));
    bool need = !__all(tm <= m_run + THR);
    float scale = 1.f;
    if (need) {
      float m_new = fmaxf(m_run, tm);
      scale = exp2f((m_run - m_new) * C2);
      m_run = m_new;
    }
    float mC = m_run * C2;
    float pv[4][4];
    float ts = 0.f;
    #pragma unroll
    for (int ni = 0; ni < 4; ++ni)
      #pragma unroll
      for (int jj = 0; jj < 4; ++jj) {
        float p = exp2f(fmaf(sa[ni][jj], C2, -mC));
        pv[ni][jj] = p;
        ts += p;
      }
    ts += __shfl_xor(ts, 16);
    ts += __shfl_xor(ts, 32);
    l_run = l_run * scale + ts;
    if (need) {
      float scq[4];
      #pragma unroll
      for (int jj = 0; jj < 4; ++jj)
        scq[jj] = __shfl(scale, kg * 4 + jj + 16 * kg);
      #pragma unroll
      for (int ni = 0; ni < 4; ++ni)
        #pragma unroll
        for (int jj = 0; jj < 4; ++jj) acc[ni][jj] *= scq[jj];
    }

    // P -> bf16 pairs, register redistribution to PV A-frag (8 shfl)
    unsigned pr[4][2];
    #pragma unroll
    for (int ni = 0; ni < 4; ++ni)
      #pragma unroll
      for (int hh = 0; hh < 2; ++hh) {
        unsigned lo = (unsigned)(unsigned short)f2bf_fast(pv[ni][2 * hh]);
        unsigned hi = (unsigned)(unsigned short)f2bf_fast(pv[ni][2 * hh + 1]);
        pr[ni][hh] = lo | (hi << 16);
      }
    union PU { s8v v; unsigned u[4]; };
    PU apu[2];
    #pragma unroll
    for (int ks = 0; ks < 2; ++ks)
      #pragma unroll
      for (int t = 0; t < 4; ++t) {
        unsigned src = (kg & 2) ? pr[2 * ks + 1][t & 1] : pr[2 * ks][t & 1];
        apu[ks].u[t] = __shfl(src, lr + 16 * (2 * (kg & 1) + (t >> 1)));
      }

    // V B-frags via hardware transpose reads
    u32x2 tr[4][2][2];
    unsigned vb = vsbase + (unsigned)(g * 2 + cur) * 8192u + vtr;
    #pragma unroll
    for (int ni = 0; ni < 4; ++ni)
      #pragma unroll
      for (int ks = 0; ks < 2; ++ks) {
        tr[ni][ks][0] = trr(vb + ni * 128 + ks * 4096);
        tr[ni][ks][1] = trr(vb + ni * 128 + ks * 4096 + 512);
      }
    asm volatile("s_waitcnt lgkmcnt(0)" ::: "memory");
    __builtin_amdgcn_sched_barrier(0);

    // O += P V
    __builtin_amdgcn_s_setprio(1);
    #pragma unroll
    for (int ni = 0; ni < 4; ++ni) {
      #pragma unroll
      for (int ks = 0; ks < 2; ++ks) {
        union { s8v v; u32x2 u2[2]; } bb;
        bb.u2[0] = tr[ni][ks][0];
        bb.u2[1] = tr[ni][ks][1];
        acc[ni] = __builtin_amdgcn_mfma_f32_16x16x32_bf16(apu[ks].v, bb.v, acc[ni], 0, 0, 0);
      }
    }
    __builtin_amdgcn_s_setprio(0);
    asm volatile("s_waitcnt lgkmcnt(0)" ::: "memory");
    asm volatile("s_waitcnt vmcnt(0)" ::: "memory");
    __builtin_amdgcn_s_barrier();
  }
#undef STAGE_K
#undef STAGE_V

  // ---- g=1: key 1024 closed form ----
  if (g) {
    s8v k0 = *(const s8v*)(Kg + 1024L * 1536 + kg * 8);
    s8v k1 = *(const s8v*)(Kg + 1024L * 1536 + 32 + kg * 8);
    float s = 0.f;
    #pragma unroll
    for (int j = 0; j < 8; ++j)
      s += bf2f(aq[0][j]) * bf2f(k0[j]) + bf2f(aq[1][j]) * bf2f(k1[j]);
    s += __shfl_xor(s, 16);
    s += __shfl_xor(s, 32);
    float m_new = fmaxf(m_run, s);
    float sc = exp2f((m_run - m_new) * C2);
    float p = exp2f((s - m_new) * C2);
    m_run = m_new;
    l_run = l_run * sc + p;
    float vrow[4];
    #pragma unroll
    for (int ni = 0; ni < 4; ++ni)
      vrow[ni] = bf2f(Vg[1024L * 1536 + ni * 16 + lr]);
    float scq[4], pq[4];
    #pragma unroll
    for (int jj = 0; jj < 4; ++jj) {
      scq[jj] = __shfl(sc, kg * 4 + jj + 16 * kg);
      pq[jj]  = __shfl(p,  kg * 4 + jj + 16 * kg);
    }
    #pragma unroll
    for (int ni = 0; ni < 4; ++ni)
      #pragma unroll
      for (int jj = 0; jj < 4; ++jj)
        acc[ni][jj] = acc[ni][jj] * scq[jj] + pq[jj] * vrow[ni];
  }

  // ---- in-block combine: LDS reuse (loop buffers dead) ----
  float* AccL = (float*)&Ks[0][0][0];     // 64x64 fp32 = 16 KB
  float* MLs  = (float*)&Vs[0][0][0];     // [2][64][2] fp32
  if (kg == 0) {
    MLs[(g * 64 + wl * 16 + lr) * 2]     = m_run;
    MLs[(g * 64 + wl * 16 + lr) * 2 + 1] = l_run;
  }
  if (g == 0) {
    #pragma unroll
    for (int ni = 0; ni < 4; ++ni)
      #pragma unroll
      for (int jj = 0; jj < 4; ++jj)
        AccL[(wl * 16 + kg * 4 + jj) * 64 + ni * 16 + lr] = acc[ni][jj];
  }
  asm volatile("s_waitcnt lgkmcnt(0)" ::: "memory");
  __builtin_amdgcn_s_barrier();
  if (g == 1) {
    float m0 = MLs[(wl * 16 + lr) * 2], l0 = MLs[(wl * 16 + lr) * 2 + 1];
    float M = fmaxf(m0, m_run);
    float w0 = exp2f((m0 - M) * C2), w1 = exp2f((m_run - M) * C2);
    float inv = 1.f / (l0 * w0 + l_run * w1);
    float c0 = w0 * inv, c1 = w1 * inv;
    float c0q[4], c1q[4];
    #pragma unroll
    for (int jj = 0; jj < 4; ++jj) {
      c0q[jj] = __shfl(c0, kg * 4 + jj + 16 * kg);
      c1q[jj] = __shfl(c1, kg * 4 + jj + 16 * kg);
    }
    #pragma unroll
    for (int ni = 0; ni < 4; ++ni)
      #pragma unroll
      for (int jj = 0; jj < 4; ++jj) {
        int row = q0 + wl * 16 + kg * 4 + jj;
        if (row < 1025) {
          float a0 = AccL[(wl * 16 + kg * 4 + jj) * 64 + ni * 16 + lr];
          O[((long)(zb * 1025 + row)) * 512 + zh * 64 + ni * 16 + lr] =
              f2bf(a0 * c0q[jj] + acc[ni][jj] * c1q[jj]);
        }
      }
  }
}

// ---------------- fused per-layer weight transpose+convert ----------------
DEV void tconv_body(const float* w, short* wt, int K, int N, int bx, int by, int tid)
{
  __shared__ float tile[32][33];
  int n0 = bx * 32, k0 = by * 32;
  int tx = tid & 31, ty = tid >> 5;
  #pragma unroll
  for (int j = 0; j < 4; ++j)
    tile[ty + j * 8][tx] = w[(long)(k0 + ty + j * 8) * N + n0 + tx];
  __syncthreads();
  #pragma unroll
  for (int j = 0; j < 4; ++j)
    wt[(long)(n0 + ty + j * 8) * K + k0 + tx] = f2bf(tile[tx][ty + j * 8]);
}

__global__ __launch_bounds__(256) void tconv4_k(
    const float* __restrict__ sq, const float* __restrict__ sm,
    const float* __restrict__ sf1, const float* __restrict__ sf2,
    short* __restrict__ dq, short* __restrict__ dm,
    short* __restrict__ df1, short* __restrict__ df2)
{
  int id = blockIdx.x, tid = threadIdx.x;
  if (id < 1152)       tconv_body(sq,  dq,  768, 1536, id % 48,          id / 48,          tid);
  else if (id < 1536)  tconv_body(sm,  dm,  512, 768,  (id - 1152) % 24, (id - 1152) / 24, tid);
  else if (id < 3072)  tconv_body(sf1, df1, 768, 2048, (id - 1536) % 64, (id - 1536) / 64, tid);
  else                 tconv_body(sf2, df2, 2048, 768, (id - 3072) % 24, (id - 3072) / 24, tid);
}

// ---------------- elementwise fp32 -> bf16 ----------------
__global__ __launch_bounds__(256) void cvt_k(const float* __restrict__ in,
    short* __restrict__ out, int n)
{
  int i = blockIdx.x * 256 + threadIdx.x;
  if (i < n) out[i] = f2bf(in[i]);
}

// ---------------- LayerNorm D=768: one wave per row, float4, no LDS ----------------
DEV void st4(float* p, f4v v) { *(f4v*)p = v; }
DEV void st4(short* p, f4v v) {
  s4v o = { f2bf(v[0]), f2bf(v[1]), f2bf(v[2]), f2bf(v[3]) };
  *(s4v*)p = o;
}

template<typename OT>
__global__ __launch_bounds__(256) void ln_k(const float* __restrict__ x,
    const float* __restrict__ g, const float* __restrict__ b,
    OT* __restrict__ y, int rows)
{
  int row = blockIdx.x * 4 + (threadIdx.x >> 6);
  if (row >= rows) return;
  int lane = threadIdx.x & 63;
  const float* xr = x + (long)row * 768;
  f4v v[3];
  #pragma unroll
  for (int i = 0; i < 3; ++i) v[i] = *(const f4v*)(xr + i * 256 + lane * 4);
  float s = 0.f, s2 = 0.f;
  #pragma unroll
  for (int i = 0; i < 3; ++i)
    #pragma unroll
    for (int j = 0; j < 4; ++j) { s += v[i][j]; s2 += v[i][j] * v[i][j]; }
  #pragma unroll
  for (int o = 1; o < 64; o <<= 1) { s += __shfl_xor(s, o); s2 += __shfl_xor(s2, o); }
  float mean = s * (1.f / 768.f);
  float var = s2 * (1.f / 768.f) - mean * mean;
  float r = rsqrtf(var + 1e-5f);
  OT* yr = y + (long)row * 768;
  #pragma unroll
  for (int i = 0; i < 3; ++i) {
    f4v gg = *(const f4v*)(g + i * 256 + lane * 4);
    f4v bb = *(const f4v*)(b + i * 256 + lane * 4);
    f4v o;
    #pragma unroll
    for (int j = 0; j < 4; ++j) o[j] = (v[i][j] - mean) * r * gg[j] + bb[j];
    st4(yr + i * 256 + lane * 4, o);
  }
}

// ---------------- patch extraction ----------------
__global__ __launch_bounds__(256) void im2col_k(const float* __restrict__ x,
    short* __restrict__ A)
{
  int i = blockIdx.x * 256 + threadIdx.x;
  int k = i & 255, row = i >> 8;
  int px = k & 15, py = k >> 4;
  int gx = row & 31, gy = (row >> 5) & 31, b = row >> 10;
  A[i] = f2bf(x[((long)(b * 512) + gy * 16 + py) * 512 + gx * 16 + px]);
}

// ---------------- t = concat(cls, tok) + pos ----------------
__global__ __launch_bounds__(256) void assemble_k(const short* __restrict__ tok,
    const float* __restrict__ cls, const float* __restrict__ pos, float* __restrict__ t)
{
  int i = blockIdx.x * 256 + threadIdx.x;
  int d = i % 768; int rn = i / 768; int n = rn % 1025; int b = rn / 1025;
  float v = (n == 0) ? cls[d] : bf2f(tok[((long)(b * 1024 + n - 1)) * 768 + d]);
  t[i] = v + pos[n * 768 + d];
}

extern "C" void kernel_launch(void* const* d_in, const int* in_sizes, int n_in,
                              void* d_out, int out_size, void* d_ws, size_t ws_size,
                              hipStream_t stream)
{
  const float* x       = (const float*)d_in[0];
  const float* conv_w  = (const float*)d_in[1];
  const float* conv_b  = (const float*)d_in[2];
  const float* cls     = (const float*)d_in[3];
  const float* pos     = (const float*)d_in[4];
  const float* qkv_w   = (const float*)d_in[5];
  const float* merge_w = (const float*)d_in[6];
  const float* merge_b = (const float*)d_in[7];
  const float* ln1_s   = (const float*)d_in[8];
  const float* ln1_b   = (const float*)d_in[9];
  const float* ln2_s   = (const float*)d_in[10];
  const float* ln2_b   = (const float*)d_in[11];
  const float* ffn_w1  = (const float*)d_in[12];
  const float* ffn_b1  = (const float*)d_in[13];
  const float* ffn_w2  = (const float*)d_in[14];
  const float* ffn_b2  = (const float*)d_in[15];
  const float* lnf_s   = (const float*)d_in[16];
  const float* lnf_b   = (const float*)d_in[17];

  char* wsp = (char*)d_ws;
  size_t o = 0;
  auto take = [&](size_t bytes) { char* r = wsp + o; o = (o + bytes + 255) & ~(size_t)255; return r; };
  short* wq   = (short*)take(1536ul * 768 * 2);
  short* wm   = (short*)take(768ul * 512 * 2);
  short* wf1  = (short*)take(2048ul * 768 * 2);
  short* wf2  = (short*)take(768ul * 2048 * 2);
  short* wcv  = (short*)take(768ul * 256 * 2);
  float* t    = (float*)take(4100ul * 768 * 4);
  char*  hO   = take(4352ul * 768 * 2);              // h bf16 OR O bf16 (rows padded)
  short* qkv  = (short*)take(4ul * 1025 * 1536 * 2);
  char*  fV   = take(4352ul * 2048 * 2);             // f (padded) OR (im2col + tok)
  take(2ul << 20);                                   // slack for tile over-reads

  short* h   = (short*)hO;
  short* O   = (short*)hO;
  short* f   = (short*)fV;
  short* imc = (short*)fV;
  short* tok = (short*)(fV + 4096ul * 256 * 2);

  dim3 blk(256), blk512(512);

  // ---- patch embed ----
  cvt_k<<<768, blk, 0, stream>>>(conv_w, wcv, 768 * 256);
  im2col_k<<<4096, blk, 0, stream>>>(x, imc);
  gemm_t<64><<<dim3(12, 64), blk, 0, stream>>>(imc, wcv, tok, conv_b,
      4096, 768, 256, 256, 256, 768, 1 | 8);
  assemble_k<<<12300, blk, 0, stream>>>(tok, cls, pos, t);

  for (int i = 0; i < 12; ++i) {
    tconv4_k<<<4608, blk, 0, stream>>>(
        qkv_w + (long)i * 768 * 1536, merge_w + (long)i * 512 * 768,
        ffn_w1 + (long)i * 768 * 2048, ffn_w2 + (long)i * 2048 * 768,
        wq, wm, wf1, wf2);

    // h = LN1(t)
    ln_k<short><<<1025, blk, 0, stream>>>(t, ln1_s + i * 768, ln1_b + i * 768, h, 4100);
    // qkv = h @ qkv_w
    gemm_t<64><<<dim3(24, 65), blk, 0, stream>>>(h, wq, qkv, nullptr,
        4100, 1536, 768, 768, 768, 1536, 8);
    // fused attention (in-block KV split) -> O
    flash_k<<<544, blk512, 0, stream>>>(qkv, O);
    // t += O @ merge_w + merge_b
    gemm_t<64><<<dim3(12, 65), blk, 0, stream>>>(O, wm, t, merge_b + i * 768,
        4100, 768, 512, 512, 512, 768, 1 | 4);
    // h = LN2(t)
    ln_k<short><<<1025, blk, 0, stream>>>(t, ln2_s + i * 768, ln2_b + i * 768, h, 4100);
    // f = GELU(h @ ffn_w1 + b1)
    gemm_t<64><<<dim3(32, 65), blk, 0, stream>>>(h, wf1, f, ffn_b1 + i * 2048,
        4100, 2048, 768, 768, 768, 2048, 1 | 2 | 8);
    // t += f @ ffn_w2 + b2
    gemm_t<64><<<dim3(12, 65), blk, 0, stream>>>(f, wf2, t, ffn_b2 + i * 768,
        4100, 768, 2048, 2048, 2048, 768, 1 | 4);
  }
  ln_k<float><<<1025, blk, 0, stream>>>(t, lnf_s, lnf_b, (float*)d_out, 4100);
}